// Round 8
// baseline (1494.449 us; speedup 1.0000x reference)
//
#include <hip/hip_runtime.h>

// DecoderGRU: h_{t+1} = GRUCell(h_t, h_t), 64 steps. Combined gates: r,z use
// (W_ih+W_hh); n keeps i_n,h_n -> one [512,1024]x[1024,4096] bf16 GEMM + fused
// GRU update per step.
// R7: ONE persistent kernel for all 64 steps. 256 blocks (1/CU), 512 thr =
// 8 waves (gate g x K-half kh). B weights in VGPRs for the whole sequence
// (asm-pinned); h + biases in regs; A (bf16 h) ping-pongs through global with
// per-rb flag sync (agent-scope release/acquire). j is XCD-local (WB slab
// 1 MB/XCD stays L2-resident -- R4's thrash bug fixed).

typedef float  f32x4 __attribute__((ext_vector_type(4)));
typedef __bf16 bf16x8 __attribute__((ext_vector_type(8)));
typedef unsigned short u16x8 __attribute__((ext_vector_type(8)));
typedef unsigned short u16x4 __attribute__((ext_vector_type(4)));

#define GPTR(p) ((const __attribute__((address_space(1))) unsigned int*)(p))
#define LPTR(p) ((__attribute__((address_space(3))) unsigned int*)(p))

// ws layout
#define WB_OFF   0u            // 8 MB frag-packed bf16 weights
#define BIAS_OFF 8388608u      // 16 KB combined biases [4][1024]
#define A0_OFF   8404992u      // 1 MB frag-packed bf16 h (ping)
#define A1_OFF   9453568u      // 1 MB (pong)
#define FLAG_OFF 10502144u     // 2 KB flags [64 t][8 rb]

__device__ __forceinline__ unsigned short f2bf(float f){
  unsigned int u = __builtin_bit_cast(unsigned int, f);
  u = (u + 0x7FFFu + ((u >> 16) & 1u)) >> 16;
  return (unsigned short)u;
}

// ---------------------------------------------------------------------------
// B layout: byte = j*262144 + c*32768 + fb*1024 + lane*16 + (k&7)*2
//   j=col>>5, c=k>>7, fb=(((k>>5)&3)*4+g)*2+((col>>4)&1),
//   lane=(col&15)+((k>>3)&3)*16.   gates: 0=r(+) 1=z(+) 2=i_n(ih) 3=h_n(hh)
// ---------------------------------------------------------------------------
extern "C" __global__ void gru_weights(const float* __restrict__ wih,
                                       const float* __restrict__ whh,
                                       char* __restrict__ WB){
  int gt  = blockIdx.x * 256 + threadIdx.x;   // 524288 threads
  int k0  = (gt & 127) << 3;                  // 8 k's per thread
  int gid = gt >> 7;
  int g   = gid >> 10, colg = gid & 1023;
  int srow = (g < 2) ? g * 1024 + colg : 2048 + colg;
  const float* pa = ((g == 3) ? whh : wih) + srow * 1024 + k0;
  f32x4 v0 = ((const f32x4*)pa)[0];
  f32x4 v1 = ((const f32x4*)pa)[1];
  if (g < 2){
    const float* pb = whh + srow * 1024 + k0;
    v0 += ((const f32x4*)pb)[0];
    v1 += ((const f32x4*)pb)[1];
  }
  u16x8 o;
  #pragma unroll
  for (int e = 0; e < 4; e++){ o[e] = f2bf(v0[e]); o[4 + e] = f2bf(v1[e]); }
  int cck = k0 >> 7;
  int fb  = (((k0 >> 5) & 3) * 4 + g) * 2 + ((colg >> 4) & 1);
  int lane= (colg & 15) + ((k0 >> 3) & 3) * 16;
  int addr= (colg >> 5) * 262144 + cck * 32768 + fb * 1024 + lane * 16;
  *(u16x8*)(WB + addr) = o;
}

// ---------------------------------------------------------------------------
// A layout: byte = (row>>6)*131072 + (hk>>7)*16384
//           + (((hk>>5)&3)*4 + ((row&63)>>4))*1024
//           + ((row&15)+((hk>>3)&3)*16)*16 + (hk&7)*2
// ---------------------------------------------------------------------------
extern "C" __global__ void gru_init(const float* __restrict__ hidden,
                                    const float* __restrict__ bih,
                                    const float* __restrict__ bhh,
                                    char* __restrict__ A0,
                                    float* __restrict__ bias,
                                    int* __restrict__ flag){
  int gt = blockIdx.x * 256 + threadIdx.x;    // 65536 threads, 8 elems each
  int e0 = gt * 8;
  int r  = e0 >> 10, c0 = e0 & 1023;
  f32x4 v0 = ((const f32x4*)(hidden + e0))[0];
  f32x4 v1 = ((const f32x4*)(hidden + e0))[1];
  u16x8 o;
  #pragma unroll
  for (int e = 0; e < 4; e++){ o[e] = f2bf(v0[e]); o[4 + e] = f2bf(v1[e]); }
  int addr = (r >> 6) * 131072 + (c0 >> 7) * 16384
           + (((c0 >> 5) & 3) * 4 + ((r & 63) >> 4)) * 1024
           + ((r & 15) + ((c0 >> 3) & 3) * 16) * 16;
  *(u16x8*)(A0 + addr) = o;
  if (blockIdx.x < 16){
    int bi = blockIdx.x * 256 + threadIdx.x;  // 4096 bias entries
    int g = bi >> 10, c = bi & 1023;
    float v = (g == 0) ? bih[c]        + bhh[c]
            : (g == 1) ? bih[1024 + c] + bhh[1024 + c]
            : (g == 2) ? bih[2048 + c] : bhh[2048 + c];
    bias[bi] = v;
  }
  if (gt < 512) flag[gt] = 0;
}

// ---------------------------------------------------------------------------
// Persistent kernel. j=(bid&7)*4+((bid>>3)&3) (WB slab XCD-local), rb=bid>>5.
// Wave wv: g=wv&3, kh=wv>>2. LDS: A triple-buffer @0/16384/32768, G @49152.
// Per step: {STAGE(c+2); setprio; 16 MFMA; vmcnt(2); barrier} x8, split-G
// epilogue, GRU update with reg-resident h/bias, Anext store, flag release;
// next step begins with flag acquire (rb-group of 32 blocks).
// ---------------------------------------------------------------------------
extern "C" __global__ void __launch_bounds__(512, 2)
gru_seq(char* __restrict__ A0p, char* __restrict__ A1p,
        const char* __restrict__ WB, const float* __restrict__ bias,
        const float* __restrict__ hidden, float* __restrict__ out,
        int* __restrict__ flag)
{
  __shared__ __align__(16) char lds[118784];
  const int tid = threadIdx.x;
  const int wv = tid >> 6, ln = tid & 63;
  const int g = wv & 3, kh = wv >> 2;
  const int lrow = ln & 15, lq = ln >> 4;
  const int bid = blockIdx.x;
  const int j  = (bid & 7) * 4 + ((bid >> 3) & 3);
  const int rb = bid >> 5;
  const int abase = rb * 131072;
  const int bbase = j * 262144;

  // ---- B into registers ONCE for all 64 steps (pinned) ----
  f32x4 braw[16][2];
  #pragma unroll
  for (int c = 0; c < 8; c++)
    #pragma unroll
    for (int p = 0; p < 2; p++)
      #pragma unroll
      for (int n = 0; n < 2; n++){
        braw[c * 2 + p][n] = *(const f32x4*)(WB + bbase + c * 32768
                               + (((kh * 2 + p) * 4 + g) * 2 + n) * 1024 + ln * 16);
        asm volatile("" : "+v"(braw[c * 2 + p][n]));
      }

  // ---- per-thread epilogue geometry; h and biases in regs ----
  const int erow = tid >> 3, ec0 = (tid & 7) * 4;
  const int grow = rb * 64 + erow, gcol = j * 32 + ec0;
  const f32x4 bR = *(const f32x4*)(bias + gcol);
  const f32x4 bZ = *(const f32x4*)(bias + 1024 + gcol);
  const f32x4 bI = *(const f32x4*)(bias + 2048 + gcol);
  const f32x4 bH = *(const f32x4*)(bias + 3072 + gcol);
  f32x4 h = *(const f32x4*)(hidden + grow * 1024 + gcol);
  const int aaddr = rb * 131072 + (j >> 2) * 16384
                  + ((j & 3) * 4 + (erow >> 4)) * 1024
                  + ((erow & 15) + ((ec0 >> 3) & 3) * 16) * 16 + (ec0 & 7) * 2;
  float* G = (float*)(lds + 49152);            // [8][64][34] f32
  const int q = kh * 4 + g;

#define STAGE(bp, cc, buf) do { \
    _Pragma("unroll") \
    for (int i = 0; i < 2; i++) \
      __builtin_amdgcn_global_load_lds( \
          GPTR((bp) + abase + (cc) * 16384 + tid * 16 + i * 8192), \
          LPTR(lds + (buf) * 16384 + tid * 16 + i * 8192), 16, 0, 0); \
  } while (0)

  for (int t = 0; t < 64; t++){
    const char* Acur = (t & 1) ? (const char*)A1p : (const char*)A0p;
    char* Anxt = (t & 1) ? A0p : A1p;
    if (t > 0){
      if (tid == 0){
        while (__hip_atomic_load(&flag[(t - 1) * 8 + rb],
                                 __ATOMIC_ACQUIRE, __HIP_MEMORY_SCOPE_AGENT) < 32)
          __builtin_amdgcn_s_sleep(1);
      }
      __syncthreads();
    }

    f32x4 acc[4][2];
    #pragma unroll
    for (int m = 0; m < 4; m++)
      #pragma unroll
      for (int n = 0; n < 2; n++) acc[m][n] = f32x4{0.f,0.f,0.f,0.f};

    STAGE(Acur, 0, 0);
    STAGE(Acur, 1, 1);
    asm volatile("s_waitcnt vmcnt(2)" ::: "memory");
    __builtin_amdgcn_s_barrier();

    #pragma unroll
    for (int c = 0; c < 8; c++){
      if (c < 6) STAGE(Acur, c + 2, (c + 2) % 3);
      __builtin_amdgcn_s_setprio(1);
      #pragma unroll
      for (int p = 0; p < 2; p++){
        const int ks = kh * 2 + p;
        bf16x8 a[4];
        #pragma unroll
        for (int m = 0; m < 4; m++)
          a[m] = *(const bf16x8*)(lds + (c % 3) * 16384 + (ks * 4 + m) * 1024 + ln * 16);
        #pragma unroll
        for (int m = 0; m < 4; m++)
          #pragma unroll
          for (int n = 0; n < 2; n++)
            acc[m][n] = __builtin_amdgcn_mfma_f32_16x16x32_bf16(
                a[m], __builtin_bit_cast(bf16x8, braw[c * 2 + p][n]), acc[m][n], 0, 0, 0);
      }
      __builtin_amdgcn_s_setprio(0);
      if (c < 6){
        asm volatile("s_waitcnt vmcnt(2)" ::: "memory");
        __builtin_amdgcn_s_barrier();
      } else if (c == 6){
        asm volatile("s_waitcnt vmcnt(0)" ::: "memory");
        __builtin_amdgcn_s_barrier();
      }
    }

    // ---- split-G epilogue (one barrier) ----
    #pragma unroll
    for (int m = 0; m < 4; m++)
      #pragma unroll
      for (int r4 = 0; r4 < 4; r4++){
        int row = m * 16 + lq * 4 + r4;
        G[q * 2176 + row * 34 + lrow]      = acc[m][0][r4];
        G[q * 2176 + row * 34 + 16 + lrow] = acc[m][1][r4];
      }
    __syncthreads();

    const int base34 = erow * 34 + ec0;
    f32x4 vr = *(const f32x4*)(G + 0 * 2176 + base34) + *(const f32x4*)(G + 4 * 2176 + base34) + bR;
    f32x4 vz = *(const f32x4*)(G + 1 * 2176 + base34) + *(const f32x4*)(G + 5 * 2176 + base34) + bZ;
    f32x4 vi = *(const f32x4*)(G + 2 * 2176 + base34) + *(const f32x4*)(G + 6 * 2176 + base34) + bI;
    f32x4 vh = *(const f32x4*)(G + 3 * 2176 + base34) + *(const f32x4*)(G + 7 * 2176 + base34) + bH;
    f32x4 vout; u16x4 hb;
    #pragma unroll
    for (int e = 0; e < 4; e++){
      float rr = 1.f / (1.f + __expf(-vr[e]));
      float zz = 1.f / (1.f + __expf(-vz[e]));
      float x  = vi[e] + rr * vh[e];
      float ex = __expf(-2.f * x);
      float nn = (1.f - ex) / (1.f + ex);
      float hn = nn + zz * (h[e] - nn);
      vout[e] = hn;
      hb[e] = f2bf(hn);
    }
    *(f32x4*)(out + (size_t)grow * 65536 + (size_t)t * 1024 + gcol) = vout;
    *(u16x4*)(Anxt + aaddr) = hb;
    h = vout;

    asm volatile("s_waitcnt vmcnt(0)" ::: "memory");
    __syncthreads();
    if (tid == 0)
      __hip_atomic_fetch_add(&flag[t * 8 + rb], 1,
                             __ATOMIC_RELEASE, __HIP_MEMORY_SCOPE_AGENT);
  }
#undef STAGE
}

// ---------------------------------------------------------------------------
extern "C" void kernel_launch(void* const* d_in, const int* in_sizes, int n_in,
                              void* d_out, int out_size, void* d_ws, size_t ws_size,
                              hipStream_t stream){
  const float* hidden = (const float*)d_in[0];
  const float* wih    = (const float*)d_in[1];
  const float* whh    = (const float*)d_in[2];
  const float* bih    = (const float*)d_in[3];
  const float* bhh    = (const float*)d_in[4];
  char*  ws   = (char*)d_ws;
  char*  WB   = ws + WB_OFF;
  float* bias = (float*)(ws + BIAS_OFF);
  char*  A0   = ws + A0_OFF;
  char*  A1   = ws + A1_OFF;
  int*   flag = (int*)(ws + FLAG_OFF);
  float* out  = (float*)d_out;

  hipLaunchKernelGGL(gru_weights, dim3(2048), dim3(256), 0, stream, wih, whh, WB);
  hipLaunchKernelGGL(gru_init,    dim3(256),  dim3(256), 0, stream,
                     hidden, bih, bhh, A0, bias, flag);
  hipLaunchKernelGGL(gru_seq,     dim3(256),  dim3(512), 0, stream,
                     A0, A1, (const char*)WB, (const float*)bias,
                     hidden, out, flag);
}

// Round 9
// 1317.922 us; speedup vs baseline: 1.1339x; 1.1339x over previous
//
#include <hip/hip_runtime.h>

// DecoderGRU: h_{t+1} = GRUCell(h_t, h_t), 64 steps. Combined gates: r,z use
// (W_ih+W_hh); n keeps i_n,h_n -> one [512,1024]x[1024,4096] bf16 GEMM + fused
// GRU update per step. 64 step launches (kernel boundary = free coherence).
// R9: tile 32 rows x 128 gate-cols, grid 512 = 2 blocks/CU (58 KB LDS) so
// exposed latencies (B preamble, stage ramp, epilogue, drain) overlap across
// co-resident blocks. B in regs/AGPRs; h_old re-read from out[t-1] (L2-hot,
// hws deleted); A triple-buffered via global_load_lds with counted vmcnt.

typedef float  f32x4 __attribute__((ext_vector_type(4)));
typedef __bf16 bf16x8 __attribute__((ext_vector_type(8)));
typedef unsigned short u16x8 __attribute__((ext_vector_type(8)));
typedef unsigned short u16x4 __attribute__((ext_vector_type(4)));

#define GPTR(p) ((const __attribute__((address_space(1))) unsigned int*)(p))
#define LPTR(p) ((__attribute__((address_space(3))) unsigned int*)(p))

// ws layout
#define WB_OFF   0u            // 8 MB frag-packed bf16 weights
#define BIAS_OFF 8388608u      // 16 KB combined biases [4][1024]
#define A0_OFF   8404992u      // 1 MB frag-packed bf16 h (ping)
#define A1_OFF   9453568u      // 1 MB (pong)

__device__ __forceinline__ unsigned short f2bf(float f){
  unsigned int u = __builtin_bit_cast(unsigned int, f);
  u = (u + 0x7FFFu + ((u >> 16) & 1u)) >> 16;
  return (unsigned short)u;
}

// ---------------------------------------------------------------------------
// B layout (unchanged from R5/R6): byte = j*262144 + c*32768 + fb*1024
//   + lane*16 + (k&7)*2,  j=col>>5, c=k>>7, fb=(((k>>5)&3)*4+g)*2+((col>>4)&1),
//   lane=(col&15)+((k>>3)&3)*16.  gates: 0=r(+) 1=z(+) 2=i_n(ih) 3=h_n(hh)
// ---------------------------------------------------------------------------
extern "C" __global__ void gru_weights(const float* __restrict__ wih,
                                       const float* __restrict__ whh,
                                       char* __restrict__ WB){
  int gt  = blockIdx.x * 256 + threadIdx.x;   // 524288 threads
  int k0  = (gt & 127) << 3;                  // 8 k's per thread
  int gid = gt >> 7;
  int g   = gid >> 10, colg = gid & 1023;
  int srow = (g < 2) ? g * 1024 + colg : 2048 + colg;
  const float* pa = ((g == 3) ? whh : wih) + srow * 1024 + k0;
  f32x4 v0 = ((const f32x4*)pa)[0];
  f32x4 v1 = ((const f32x4*)pa)[1];
  if (g < 2){
    const float* pb = whh + srow * 1024 + k0;
    v0 += ((const f32x4*)pb)[0];
    v1 += ((const f32x4*)pb)[1];
  }
  u16x8 o;
  #pragma unroll
  for (int e = 0; e < 4; e++){ o[e] = f2bf(v0[e]); o[4 + e] = f2bf(v1[e]); }
  int cck = k0 >> 7;
  int fb  = (((k0 >> 5) & 3) * 4 + g) * 2 + ((colg >> 4) & 1);
  int lane= (colg & 15) + ((k0 >> 3) & 3) * 16;
  int addr= (colg >> 5) * 262144 + cck * 32768 + fb * 1024 + lane * 16;
  *(u16x8*)(WB + addr) = o;
}

// ---------------------------------------------------------------------------
// A layout (32-row slabs): byte = (row>>5)*65536 + (hk>>7)*8192
//   + (((hk>>5)&3)*2 + ((row&31)>>4))*1024
//   + ((row&15)+((hk>>3)&3)*16)*16 + (hk&7)*2
// ---------------------------------------------------------------------------
extern "C" __global__ void gru_init(const float* __restrict__ hidden,
                                    const float* __restrict__ bih,
                                    const float* __restrict__ bhh,
                                    char* __restrict__ A0,
                                    float* __restrict__ bias){
  int gt = blockIdx.x * 256 + threadIdx.x;    // 65536 threads, 8 elems each
  int e0 = gt * 8;
  int r  = e0 >> 10, c0 = e0 & 1023;
  f32x4 v0 = ((const f32x4*)(hidden + e0))[0];
  f32x4 v1 = ((const f32x4*)(hidden + e0))[1];
  u16x8 o;
  #pragma unroll
  for (int e = 0; e < 4; e++){ o[e] = f2bf(v0[e]); o[4 + e] = f2bf(v1[e]); }
  int addr = (r >> 5) * 65536 + (c0 >> 7) * 8192
           + (((c0 >> 5) & 3) * 2 + ((r & 31) >> 4)) * 1024
           + ((r & 15) + ((c0 >> 3) & 3) * 16) * 16;
  *(u16x8*)(A0 + addr) = o;
  if (blockIdx.x < 16){
    int bi = blockIdx.x * 256 + threadIdx.x;  // 4096 bias entries
    int g = bi >> 10, c = bi & 1023;
    float v = (g == 0) ? bih[c]        + bhh[c]
            : (g == 1) ? bih[1024 + c] + bhh[1024 + c]
            : (g == 2) ? bih[2048 + c] : bhh[2048 + c];
    bias[bi] = v;
  }
}

// ---------------------------------------------------------------------------
// Step kernel. grid 512 (2 blocks/CU), 512 thr = 8 waves = (gate g, K-half kh).
// rb=bid>>5 (32-row slab), j=(bid&7)*4+((bid>>3)&3) (WB slab XCD-local).
// B in regs/AGPRs: b[16][2] bf16x8 (128 regs). A triple-buffer 3x8KB @0;
// G split-regions [8][32][34] f32 @24576 (total 59392 B LDS).
// K-loop: {STAGE(c+2); setprio(1); 8 MFMA; setprio(0); vmcnt(1); barrier}.
// ---------------------------------------------------------------------------
extern "C" __global__ void __launch_bounds__(512, 4)
gru_step(const char* __restrict__ Acur, char* __restrict__ Anext,
         const char* __restrict__ WB, const float* __restrict__ bias,
         const float* __restrict__ hidden, float* __restrict__ out, int t)
{
  __shared__ __align__(16) char lds[59392];
  const int tid = threadIdx.x;
  const int wv = tid >> 6, ln = tid & 63;
  const int g = wv & 3, kh = wv >> 2;
  const int lrow = ln & 15, lq = ln >> 4;
  const int bid = blockIdx.x;
  const int j  = (bid & 7) * 4 + ((bid >> 3) & 3);
  const int rb = bid >> 5;
  const int abase = rb * 65536;
  const int bbase = j * 262144;

  // ---- B into registers (AGPR-eligible; MFMA reads them directly) ----
  f32x4 braw[16][2];
  #pragma unroll
  for (int c = 0; c < 8; c++)
    #pragma unroll
    for (int p = 0; p < 2; p++)
      #pragma unroll
      for (int n = 0; n < 2; n++){
        braw[c * 2 + p][n] = *(const f32x4*)(WB + bbase + c * 32768
                               + (((kh * 2 + p) * 4 + g) * 2 + n) * 1024 + ln * 16);
        asm volatile("" : "+v"(braw[c * 2 + p][n]));
      }

  f32x4 acc[2][2];
  #pragma unroll
  for (int m = 0; m < 2; m++)
    #pragma unroll
    for (int n = 0; n < 2; n++) acc[m][n] = f32x4{0.f,0.f,0.f,0.f};

#define STAGE(cc, buf) \
    __builtin_amdgcn_global_load_lds( \
        GPTR(Acur + abase + (cc) * 8192 + tid * 16), \
        LPTR(lds + (buf) * 8192 + tid * 16), 16, 0, 0)

  STAGE(0, 0);
  STAGE(1, 1);
  asm volatile("s_waitcnt vmcnt(1)" ::: "memory");
  __builtin_amdgcn_s_barrier();

  #pragma unroll
  for (int c = 0; c < 8; c++){
    if (c < 6) STAGE(c + 2, (c + 2) % 3);
    __builtin_amdgcn_s_setprio(1);
    #pragma unroll
    for (int p = 0; p < 2; p++){
      const int ks = kh * 2 + p;
      bf16x8 a[2];
      #pragma unroll
      for (int m = 0; m < 2; m++)
        a[m] = *(const bf16x8*)(lds + (c % 3) * 8192 + (ks * 2 + m) * 1024 + ln * 16);
      #pragma unroll
      for (int m = 0; m < 2; m++)
        #pragma unroll
        for (int n = 0; n < 2; n++)
          acc[m][n] = __builtin_amdgcn_mfma_f32_16x16x32_bf16(
              a[m], __builtin_bit_cast(bf16x8, braw[c * 2 + p][n]), acc[m][n], 0, 0, 0);
    }
    __builtin_amdgcn_s_setprio(0);
    if (c < 6){
      asm volatile("s_waitcnt vmcnt(1)" ::: "memory");
      __builtin_amdgcn_s_barrier();
    } else if (c == 6){
      asm volatile("s_waitcnt vmcnt(0)" ::: "memory");
      __builtin_amdgcn_s_barrier();
    }
  }
#undef STAGE

  // ---- split-G epilogue: G[q][32 rows][34], q=kh*4+g; one barrier ----
  float* G = (float*)(lds + 24576);
  const int q = kh * 4 + g;
  #pragma unroll
  for (int m = 0; m < 2; m++)
    #pragma unroll
    for (int r4 = 0; r4 < 4; r4++){
      int row = m * 16 + lq * 4 + r4;
      G[q * 1088 + row * 34 + lrow]      = acc[m][0][r4];
      G[q * 1088 + row * 34 + 16 + lrow] = acc[m][1][r4];
    }
  __syncthreads();

  if (tid < 256){
    const int erow = tid >> 3, ec0 = (tid & 7) * 4;
    const int base34 = erow * 34 + ec0;
    const int grow = rb * 32 + erow;
    const int gcol = j * 32 + ec0;
    f32x4 vr = *(const f32x4*)(G + 0 * 1088 + base34) + *(const f32x4*)(G + 4 * 1088 + base34)
             + *(const f32x4*)(bias + gcol);
    f32x4 vz = *(const f32x4*)(G + 1 * 1088 + base34) + *(const f32x4*)(G + 5 * 1088 + base34)
             + *(const f32x4*)(bias + 1024 + gcol);
    f32x4 vi = *(const f32x4*)(G + 2 * 1088 + base34) + *(const f32x4*)(G + 6 * 1088 + base34)
             + *(const f32x4*)(bias + 2048 + gcol);
    f32x4 vh = *(const f32x4*)(G + 3 * 1088 + base34) + *(const f32x4*)(G + 7 * 1088 + base34)
             + *(const f32x4*)(bias + 3072 + gcol);
    f32x4 hold = (t == 0)
        ? *(const f32x4*)(hidden + grow * 1024 + gcol)
        : *(const f32x4*)(out + (size_t)grow * 65536 + (size_t)(t - 1) * 1024 + gcol);
    f32x4 vout; u16x4 hb;
    #pragma unroll
    for (int e = 0; e < 4; e++){
      float rr = 1.f / (1.f + __expf(-vr[e]));
      float zz = 1.f / (1.f + __expf(-vz[e]));
      float x  = vi[e] + rr * vh[e];
      float ex = __expf(-2.f * x);
      float nn = (1.f - ex) / (1.f + ex);
      float hn = nn + zz * (hold[e] - nn);
      vout[e] = hn;
      hb[e] = f2bf(hn);
    }
    *(f32x4*)(out + (size_t)grow * 65536 + (size_t)t * 1024 + gcol) = vout;
    int aaddr = rb * 65536 + (j >> 2) * 8192
              + ((j & 3) * 2 + (erow >> 4)) * 1024
              + ((erow & 15) + (ec0 >> 3) * 16) * 16 + (ec0 & 4) * 2;
    *(u16x4*)(Anext + aaddr) = hb;
  }
}

// ---------------------------------------------------------------------------
extern "C" void kernel_launch(void* const* d_in, const int* in_sizes, int n_in,
                              void* d_out, int out_size, void* d_ws, size_t ws_size,
                              hipStream_t stream){
  const float* hidden = (const float*)d_in[0];
  const float* wih    = (const float*)d_in[1];
  const float* whh    = (const float*)d_in[2];
  const float* bih    = (const float*)d_in[3];
  const float* bhh    = (const float*)d_in[4];
  char*  ws   = (char*)d_ws;
  char*  WB   = ws + WB_OFF;
  float* bias = (float*)(ws + BIAS_OFF);
  char*  A0   = ws + A0_OFF;
  char*  A1   = ws + A1_OFF;
  float* out  = (float*)d_out;

  hipLaunchKernelGGL(gru_weights, dim3(2048), dim3(256), 0, stream, wih, whh, WB);
  hipLaunchKernelGGL(gru_init,    dim3(256),  dim3(256), 0, stream,
                     hidden, bih, bhh, A0, bias);
  for (int t = 0; t < 64; t++){
    char* Asrc = (t & 1) ? A1 : A0;
    char* Adst = (t & 1) ? A0 : A1;
    hipLaunchKernelGGL(gru_step, dim3(512), dim3(512), 0, stream,
                       (const char*)Asrc, Adst,
                       (const char*)WB, (const float*)bias, hidden, out, t);
  }
}

// Round 10
// 727.870 us; speedup vs baseline: 2.0532x; 1.8107x over previous
//
#include <hip/hip_runtime.h>

// DecoderGRU: h_{t+1} = GRUCell(h_t, h_t), 64 steps. Combined gates: r,z use
// (W_ih+W_hh); n keeps i_n,h_n -> one [512,1024]x[1024,4096] bf16 GEMM + fused
// GRU update per step. 64 step launches (kernel boundary = free coherence).
// R10: tile 32 rows x 128 gate-cols, grid 512 = 2 blocks/CU. B streamed
// per-chunk into a 3-slot register ring (48 regs live, no spill at the
// 128-reg/thread budget) -> B-preamble exposure gone, compiler emits counted
// vmcnt for B-reg uses (T4). A triple-buffered via global_load_lds with
// manual vmcnt(9) gating only the staging. h_old re-read from out[t-1].

typedef float  f32x4 __attribute__((ext_vector_type(4)));
typedef __bf16 bf16x8 __attribute__((ext_vector_type(8)));
typedef unsigned short u16x8 __attribute__((ext_vector_type(8)));
typedef unsigned short u16x4 __attribute__((ext_vector_type(4)));

#define GPTR(p) ((const __attribute__((address_space(1))) unsigned int*)(p))
#define LPTR(p) ((__attribute__((address_space(3))) unsigned int*)(p))

// ws layout
#define WB_OFF   0u            // 8 MB frag-packed bf16 weights
#define BIAS_OFF 8388608u      // 16 KB combined biases [4][1024]
#define A0_OFF   8404992u      // 1 MB frag-packed bf16 h (ping)
#define A1_OFF   9453568u      // 1 MB (pong)

__device__ __forceinline__ unsigned short f2bf(float f){
  unsigned int u = __builtin_bit_cast(unsigned int, f);
  u = (u + 0x7FFFu + ((u >> 16) & 1u)) >> 16;
  return (unsigned short)u;
}

// ---------------------------------------------------------------------------
// B layout: byte = j*262144 + c*32768 + fb*1024 + lane*16 + (k&7)*2,
//   j=col>>5, c=k>>7, fb=(((k>>5)&3)*4+g)*2+((col>>4)&1),
//   lane=(col&15)+((k>>3)&3)*16.  gates: 0=r(+) 1=z(+) 2=i_n(ih) 3=h_n(hh)
// ---------------------------------------------------------------------------
extern "C" __global__ void gru_weights(const float* __restrict__ wih,
                                       const float* __restrict__ whh,
                                       char* __restrict__ WB){
  int gt  = blockIdx.x * 256 + threadIdx.x;   // 524288 threads
  int k0  = (gt & 127) << 3;                  // 8 k's per thread
  int gid = gt >> 7;
  int g   = gid >> 10, colg = gid & 1023;
  int srow = (g < 2) ? g * 1024 + colg : 2048 + colg;
  const float* pa = ((g == 3) ? whh : wih) + srow * 1024 + k0;
  f32x4 v0 = ((const f32x4*)pa)[0];
  f32x4 v1 = ((const f32x4*)pa)[1];
  if (g < 2){
    const float* pb = whh + srow * 1024 + k0;
    v0 += ((const f32x4*)pb)[0];
    v1 += ((const f32x4*)pb)[1];
  }
  u16x8 o;
  #pragma unroll
  for (int e = 0; e < 4; e++){ o[e] = f2bf(v0[e]); o[4 + e] = f2bf(v1[e]); }
  int cck = k0 >> 7;
  int fb  = (((k0 >> 5) & 3) * 4 + g) * 2 + ((colg >> 4) & 1);
  int lane= (colg & 15) + ((k0 >> 3) & 3) * 16;
  int addr= (colg >> 5) * 262144 + cck * 32768 + fb * 1024 + lane * 16;
  *(u16x8*)(WB + addr) = o;
}

// ---------------------------------------------------------------------------
// A layout (32-row slabs): byte = (row>>5)*65536 + (hk>>7)*8192
//   + (((hk>>5)&3)*2 + ((row&31)>>4))*1024
//   + ((row&15)+((hk>>3)&3)*16)*16 + (hk&7)*2
// ---------------------------------------------------------------------------
extern "C" __global__ void gru_init(const float* __restrict__ hidden,
                                    const float* __restrict__ bih,
                                    const float* __restrict__ bhh,
                                    char* __restrict__ A0,
                                    float* __restrict__ bias){
  int gt = blockIdx.x * 256 + threadIdx.x;    // 65536 threads, 8 elems each
  int e0 = gt * 8;
  int r  = e0 >> 10, c0 = e0 & 1023;
  f32x4 v0 = ((const f32x4*)(hidden + e0))[0];
  f32x4 v1 = ((const f32x4*)(hidden + e0))[1];
  u16x8 o;
  #pragma unroll
  for (int e = 0; e < 4; e++){ o[e] = f2bf(v0[e]); o[4 + e] = f2bf(v1[e]); }
  int addr = (r >> 5) * 65536 + (c0 >> 7) * 8192
           + (((c0 >> 5) & 3) * 2 + ((r & 31) >> 4)) * 1024
           + ((r & 15) + ((c0 >> 3) & 3) * 16) * 16;
  *(u16x8*)(A0 + addr) = o;
  if (blockIdx.x < 16){
    int bi = blockIdx.x * 256 + threadIdx.x;  // 4096 bias entries
    int g = bi >> 10, c = bi & 1023;
    float v = (g == 0) ? bih[c]        + bhh[c]
            : (g == 1) ? bih[1024 + c] + bhh[1024 + c]
            : (g == 2) ? bih[2048 + c] : bhh[2048 + c];
    bias[bi] = v;
  }
}

// ---------------------------------------------------------------------------
// Step kernel. grid 512 (2 blocks/CU), 512 thr = 8 waves = (gate g, K-half kh).
// rb=bid>>5 (32-row slab), j=(bid&7)*4+((bid>>3)&3) (WB slab XCD-local).
// B: 3-slot register ring bf[3][4], chunk c+2 loaded while computing c.
// A: triple-buffer 3x8KB @0; G split-regions [8][32][34] f32 @24576.
// Iter: {STAGE(c+2); BLOAD(c+2); setprio(1); 8 MFMA; setprio(0); vmcnt(9); bar}.
// ---------------------------------------------------------------------------
extern "C" __global__ void __launch_bounds__(512, 4)
gru_step(const char* __restrict__ Acur, char* __restrict__ Anext,
         const char* __restrict__ WB, const float* __restrict__ bias,
         const float* __restrict__ hidden, float* __restrict__ out, int t)
{
  __shared__ __align__(16) char lds[59392];
  const int tid = threadIdx.x;
  const int wv = tid >> 6, ln = tid & 63;
  const int g = wv & 3, kh = wv >> 2;
  const int lrow = ln & 15, lq = ln >> 4;
  const int bid = blockIdx.x;
  const int j  = (bid & 7) * 4 + ((bid >> 3) & 3);
  const int rb = bid >> 5;
  const int abase = rb * 65536;
  const int bbase = j * 262144;

  f32x4 bf[3][4];          // B ring: [slot][p*2+n], static-indexed after unroll
  f32x4 acc[2][2];
  #pragma unroll
  for (int m = 0; m < 2; m++)
    #pragma unroll
    for (int n = 0; n < 2; n++) acc[m][n] = f32x4{0.f,0.f,0.f,0.f};

#define STAGE(cc, buf) \
    __builtin_amdgcn_global_load_lds( \
        GPTR(Acur + abase + (cc) * 8192 + tid * 16), \
        LPTR(lds + (buf) * 8192 + tid * 16), 16, 0, 0)

#define BLOAD(cc, slot) do { \
    _Pragma("unroll") \
    for (int p = 0; p < 2; p++) \
      _Pragma("unroll") \
      for (int n = 0; n < 2; n++) \
        bf[slot][p * 2 + n] = *(const f32x4*)(WB + bbase + (cc) * 32768 \
            + (((kh * 2 + p) * 4 + g) * 2 + n) * 1024 + ln * 16); \
  } while (0)

  STAGE(0, 0);
  BLOAD(0, 0);
  STAGE(1, 1);
  BLOAD(1, 1);
  asm volatile("s_waitcnt vmcnt(9)" ::: "memory");   // A(0) done; rest in flight
  __builtin_amdgcn_s_barrier();

  #pragma unroll
  for (int c = 0; c < 8; c++){
    if (c < 6){
      STAGE(c + 2, (c + 2) % 3);
      BLOAD(c + 2, (c + 2) % 3);
    }
    __builtin_amdgcn_s_setprio(1);
    #pragma unroll
    for (int p = 0; p < 2; p++){
      const int ks = kh * 2 + p;
      bf16x8 a[2];
      #pragma unroll
      for (int m = 0; m < 2; m++)
        a[m] = *(const bf16x8*)(lds + (c % 3) * 8192 + (ks * 2 + m) * 1024 + ln * 16);
      #pragma unroll
      for (int m = 0; m < 2; m++)
        #pragma unroll
        for (int n = 0; n < 2; n++)
          acc[m][n] = __builtin_amdgcn_mfma_f32_16x16x32_bf16(
              a[m], __builtin_bit_cast(bf16x8, bf[c % 3][p * 2 + n]), acc[m][n], 0, 0, 0);
    }
    __builtin_amdgcn_s_setprio(0);
    if (c < 6){
      asm volatile("s_waitcnt vmcnt(9)" ::: "memory");  // A(c+1) done
      __builtin_amdgcn_s_barrier();
    } else if (c == 6){
      asm volatile("s_waitcnt vmcnt(4)" ::: "memory");  // A(7) done
      __builtin_amdgcn_s_barrier();
    }
  }
#undef STAGE
#undef BLOAD

  // ---- split-G epilogue: G[q][32 rows][34], q=kh*4+g; one barrier ----
  float* G = (float*)(lds + 24576);
  const int q = kh * 4 + g;
  #pragma unroll
  for (int m = 0; m < 2; m++)
    #pragma unroll
    for (int r4 = 0; r4 < 4; r4++){
      int row = m * 16 + lq * 4 + r4;
      G[q * 1088 + row * 34 + lrow]      = acc[m][0][r4];
      G[q * 1088 + row * 34 + 16 + lrow] = acc[m][1][r4];
    }
  __syncthreads();

  if (tid < 256){
    const int erow = tid >> 3, ec0 = (tid & 7) * 4;
    const int base34 = erow * 34 + ec0;
    const int grow = rb * 32 + erow;
    const int gcol = j * 32 + ec0;
    f32x4 vr = *(const f32x4*)(G + 0 * 1088 + base34) + *(const f32x4*)(G + 4 * 1088 + base34)
             + *(const f32x4*)(bias + gcol);
    f32x4 vz = *(const f32x4*)(G + 1 * 1088 + base34) + *(const f32x4*)(G + 5 * 1088 + base34)
             + *(const f32x4*)(bias + 1024 + gcol);
    f32x4 vi = *(const f32x4*)(G + 2 * 1088 + base34) + *(const f32x4*)(G + 6 * 1088 + base34)
             + *(const f32x4*)(bias + 2048 + gcol);
    f32x4 vh = *(const f32x4*)(G + 3 * 1088 + base34) + *(const f32x4*)(G + 7 * 1088 + base34)
             + *(const f32x4*)(bias + 3072 + gcol);
    f32x4 hold = (t == 0)
        ? *(const f32x4*)(hidden + grow * 1024 + gcol)
        : *(const f32x4*)(out + (size_t)grow * 65536 + (size_t)(t - 1) * 1024 + gcol);
    f32x4 vout; u16x4 hb;
    #pragma unroll
    for (int e = 0; e < 4; e++){
      float rr = 1.f / (1.f + __expf(-vr[e]));
      float zz = 1.f / (1.f + __expf(-vz[e]));
      float x  = vi[e] + rr * vh[e];
      float ex = __expf(-2.f * x);
      float nn = (1.f - ex) / (1.f + ex);
      float hn = nn + zz * (hold[e] - nn);
      vout[e] = hn;
      hb[e] = f2bf(hn);
    }
    *(f32x4*)(out + (size_t)grow * 65536 + (size_t)t * 1024 + gcol) = vout;
    int aaddr = rb * 65536 + (j >> 2) * 8192
              + ((j & 3) * 2 + (erow >> 4)) * 1024
              + ((erow & 15) + (ec0 >> 3) * 16) * 16 + (ec0 & 4) * 2;
    *(u16x4*)(Anext + aaddr) = hb;
  }
}

// ---------------------------------------------------------------------------
extern "C" void kernel_launch(void* const* d_in, const int* in_sizes, int n_in,
                              void* d_out, int out_size, void* d_ws, size_t ws_size,
                              hipStream_t stream){
  const float* hidden = (const float*)d_in[0];
  const float* wih    = (const float*)d_in[1];
  const float* whh    = (const float*)d_in[2];
  const float* bih    = (const float*)d_in[3];
  const float* bhh    = (const float*)d_in[4];
  char*  ws   = (char*)d_ws;
  char*  WB   = ws + WB_OFF;
  float* bias = (float*)(ws + BIAS_OFF);
  char*  A0   = ws + A0_OFF;
  char*  A1   = ws + A1_OFF;
  float* out  = (float*)d_out;

  hipLaunchKernelGGL(gru_weights, dim3(2048), dim3(256), 0, stream, wih, whh, WB);
  hipLaunchKernelGGL(gru_init,    dim3(256),  dim3(256), 0, stream,
                     hidden, bih, bhh, A0, bias);
  for (int t = 0; t < 64; t++){
    char* Asrc = (t & 1) ? A1 : A0;
    char* Adst = (t & 1) ? A0 : A1;
    hipLaunchKernelGGL(gru_step, dim3(512), dim3(512), 0, stream,
                       (const char*)Asrc, Adst,
                       (const char*)WB, (const float*)bias, hidden, out, t);
  }
}

// Round 11
// 493.676 us; speedup vs baseline: 3.0272x; 1.4744x over previous
//
#include <hip/hip_runtime.h>

// DecoderGRU: h_{t+1} = GRUCell(h_t, h_t), 64 steps. Combined gates: r,z use
// (W_ih+W_hh); n keeps i_n,h_n -> one [512,1024]x[1024,4096] bf16 GEMM + fused
// GRU update per step.
// R11: persistent kernel v3. 256 blocks (1/CU), 512 thr = 8 waves (gate x
// K-half). B in regs for the whole sequence under a 256-reg budget
// (__launch_bounds__(512,1) -- R8's 128-cap spill bug fixed). A exchange is
// point-to-point through the LLC: sc1 stores (system-relaxed atomics) +
// sc1 global_load_lds (aux=17) + system-relaxed flag atomics. NO acquire/
// release cache maintenance -> per-XCD L2 (holding WB) never invalidated.
// rb=bid&7 makes each 32-block sync group XCD-local (perf only, not
// correctness). 4-deep A ring hides LLC latency.

typedef float  f32x4 __attribute__((ext_vector_type(4)));
typedef __bf16 bf16x8 __attribute__((ext_vector_type(8)));
typedef unsigned short u16x8 __attribute__((ext_vector_type(8)));
typedef unsigned short u16x4 __attribute__((ext_vector_type(4)));

#define GPTR(p) ((const __attribute__((address_space(1))) unsigned int*)(p))
#define LPTR(p) ((__attribute__((address_space(3))) unsigned int*)(p))

// ws layout
#define WB_OFF   0u            // 8 MB frag-packed bf16 weights
#define BIAS_OFF 8388608u      // 16 KB combined biases [4][1024]
#define A0_OFF   8404992u      // 1 MB frag-packed bf16 h (ping)
#define A1_OFF   9453568u      // 1 MB (pong)
#define FLAG_OFF 10502144u     // 2 KB flags [64 t][8 rb]

__device__ __forceinline__ unsigned short f2bf(float f){
  unsigned int u = __builtin_bit_cast(unsigned int, f);
  u = (u + 0x7FFFu + ((u >> 16) & 1u)) >> 16;
  return (unsigned short)u;
}

// ---------------------------------------------------------------------------
// B layout: byte = j*262144 + c*32768 + fb*1024 + lane*16 + (k&7)*2,
//   j=col>>5, c=k>>7, fb=(((k>>5)&3)*4+g)*2+((col>>4)&1),
//   lane=(col&15)+((k>>3)&3)*16.  gates: 0=r(+) 1=z(+) 2=i_n(ih) 3=h_n(hh)
// ---------------------------------------------------------------------------
extern "C" __global__ void gru_weights(const float* __restrict__ wih,
                                       const float* __restrict__ whh,
                                       char* __restrict__ WB){
  int gt  = blockIdx.x * 256 + threadIdx.x;   // 524288 threads
  int k0  = (gt & 127) << 3;                  // 8 k's per thread
  int gid = gt >> 7;
  int g   = gid >> 10, colg = gid & 1023;
  int srow = (g < 2) ? g * 1024 + colg : 2048 + colg;
  const float* pa = ((g == 3) ? whh : wih) + srow * 1024 + k0;
  f32x4 v0 = ((const f32x4*)pa)[0];
  f32x4 v1 = ((const f32x4*)pa)[1];
  if (g < 2){
    const float* pb = whh + srow * 1024 + k0;
    v0 += ((const f32x4*)pb)[0];
    v1 += ((const f32x4*)pb)[1];
  }
  u16x8 o;
  #pragma unroll
  for (int e = 0; e < 4; e++){ o[e] = f2bf(v0[e]); o[4 + e] = f2bf(v1[e]); }
  int cck = k0 >> 7;
  int fb  = (((k0 >> 5) & 3) * 4 + g) * 2 + ((colg >> 4) & 1);
  int lane= (colg & 15) + ((k0 >> 3) & 3) * 16;
  int addr= (colg >> 5) * 262144 + cck * 32768 + fb * 1024 + lane * 16;
  *(u16x8*)(WB + addr) = o;
}

// ---------------------------------------------------------------------------
// A layout (64-row slabs): byte = (row>>6)*131072 + (hk>>7)*16384
//   + (((hk>>5)&3)*4 + ((row&63)>>4))*1024
//   + ((row&15)+((hk>>3)&3)*16)*16 + (hk&7)*2
// ---------------------------------------------------------------------------
extern "C" __global__ void gru_init(const float* __restrict__ hidden,
                                    const float* __restrict__ bih,
                                    const float* __restrict__ bhh,
                                    char* __restrict__ A0,
                                    float* __restrict__ bias,
                                    int* __restrict__ flag){
  int gt = blockIdx.x * 256 + threadIdx.x;    // 65536 threads, 8 elems each
  int e0 = gt * 8;
  int r  = e0 >> 10, c0 = e0 & 1023;
  f32x4 v0 = ((const f32x4*)(hidden + e0))[0];
  f32x4 v1 = ((const f32x4*)(hidden + e0))[1];
  u16x8 o;
  #pragma unroll
  for (int e = 0; e < 4; e++){ o[e] = f2bf(v0[e]); o[4 + e] = f2bf(v1[e]); }
  int addr = (r >> 6) * 131072 + (c0 >> 7) * 16384
           + (((c0 >> 5) & 3) * 4 + ((r & 63) >> 4)) * 1024
           + ((r & 15) + ((c0 >> 3) & 3) * 16) * 16;
  *(u16x8*)(A0 + addr) = o;
  if (blockIdx.x < 16){
    int bi = blockIdx.x * 256 + threadIdx.x;  // 4096 bias entries
    int g = bi >> 10, c = bi & 1023;
    float v = (g == 0) ? bih[c]        + bhh[c]
            : (g == 1) ? bih[1024 + c] + bhh[1024 + c]
            : (g == 2) ? bih[2048 + c] : bhh[2048 + c];
    bias[bi] = v;
  }
  if (gt < 512) flag[gt] = 0;
}

// ---------------------------------------------------------------------------
// Persistent kernel v3. rb=bid&7 (sync group, XCD-local under round-robin),
// j=bid>>3 (B slab). Wave wv: g=wv&3, kh=wv>>2.
// LDS: A 4-ring @0 (4x16KB), G split-regions [8][64][34] f32 @65536.
// Per step: poll flag[t-1,rb] -> 4-deep pipelined A staging (sc1) + 16 MFMA
// per chunk -> split-G epilogue -> out store + sc1 Anext store -> vmcnt(0),
// barrier, flag[t,rb] += 1 (system-relaxed).
// ---------------------------------------------------------------------------
extern "C" __global__ void __launch_bounds__(512, 1)
gru_seq(char* __restrict__ A0p, char* __restrict__ A1p,
        const char* __restrict__ WB, const float* __restrict__ bias,
        const float* __restrict__ hidden, float* __restrict__ out,
        int* __restrict__ flag)
{
  __shared__ __align__(16) char lds[135168];
  const int tid = threadIdx.x;
  const int wv = tid >> 6, ln = tid & 63;
  const int g = wv & 3, kh = wv >> 2;
  const int lrow = ln & 15, lq = ln >> 4;
  const int bid = blockIdx.x;
  const int rb = bid & 7, j = bid >> 3;
  const int abase = rb * 131072;
  const int bbase = j * 262144;

  // ---- B into registers ONCE for all 64 steps ----
  f32x4 braw[16][2];
  #pragma unroll
  for (int c = 0; c < 8; c++)
    #pragma unroll
    for (int p = 0; p < 2; p++)
      #pragma unroll
      for (int n = 0; n < 2; n++){
        braw[c * 2 + p][n] = *(const f32x4*)(WB + bbase + c * 32768
                               + (((kh * 2 + p) * 4 + g) * 2 + n) * 1024 + ln * 16);
        asm volatile("" : "+v"(braw[c * 2 + p][n]));
      }

  // ---- per-thread epilogue geometry; h and biases in regs ----
  const int erow = tid >> 3, ec0 = (tid & 7) * 4;
  const int grow = rb * 64 + erow, gcol = j * 32 + ec0;
  const f32x4 bR = *(const f32x4*)(bias + gcol);
  const f32x4 bZ = *(const f32x4*)(bias + 1024 + gcol);
  const f32x4 bI = *(const f32x4*)(bias + 2048 + gcol);
  const f32x4 bH = *(const f32x4*)(bias + 3072 + gcol);
  f32x4 h = *(const f32x4*)(hidden + grow * 1024 + gcol);
  const int aaddr = rb * 131072 + (j >> 2) * 16384
                  + ((j & 3) * 4 + (erow >> 4)) * 1024
                  + ((erow & 15) + ((ec0 >> 3) & 3) * 16) * 16 + (ec0 & 7) * 2;
  float* G = (float*)(lds + 65536);            // [8][64][34] f32
  const int q = kh * 4 + g;

// sc1 staging: aux = 17 (sc0|sc1) -> bypass L1/L2, read at LLC (coherent).
#define STAGE(bp, cc) do { \
    _Pragma("unroll") \
    for (int i = 0; i < 2; i++) \
      __builtin_amdgcn_global_load_lds( \
          GPTR((bp) + abase + (cc) * 16384 + tid * 16 + i * 8192), \
          LPTR(lds + ((cc) & 3) * 16384 + tid * 16 + i * 8192), 16, 0, 17); \
  } while (0)

  for (int t = 0; t < 64; t++){
    const char* Acur = (t & 1) ? (const char*)A1p : (const char*)A0p;
    char* Anxt = (t & 1) ? A0p : A1p;
    if (t > 0){
      if (tid == 0){
        while (__hip_atomic_load(&flag[(t - 1) * 8 + rb],
                                 __ATOMIC_RELAXED, __HIP_MEMORY_SCOPE_SYSTEM) < 32)
          __builtin_amdgcn_s_sleep(1);
      }
      __syncthreads();
      asm volatile("" ::: "memory");
    }

    f32x4 acc[4][2];
    #pragma unroll
    for (int m = 0; m < 4; m++)
      #pragma unroll
      for (int n = 0; n < 2; n++) acc[m][n] = f32x4{0.f,0.f,0.f,0.f};

    STAGE(Acur, 0);
    STAGE(Acur, 1);
    STAGE(Acur, 2);
    asm volatile("s_waitcnt vmcnt(4)" ::: "memory");   // chunk 0 resident
    __builtin_amdgcn_s_barrier();

    #pragma unroll
    for (int c = 0; c < 8; c++){
      if (c < 5) STAGE(Acur, c + 3);
      __builtin_amdgcn_s_setprio(1);
      #pragma unroll
      for (int p = 0; p < 2; p++){
        const int ks = kh * 2 + p;
        bf16x8 a[4];
        #pragma unroll
        for (int m = 0; m < 4; m++)
          a[m] = *(const bf16x8*)(lds + (c & 3) * 16384 + (ks * 4 + m) * 1024 + ln * 16);
        #pragma unroll
        for (int m = 0; m < 4; m++)
          #pragma unroll
          for (int n = 0; n < 2; n++)
            acc[m][n] = __builtin_amdgcn_mfma_f32_16x16x32_bf16(
                a[m], __builtin_bit_cast(bf16x8, braw[c * 2 + p][n]), acc[m][n], 0, 0, 0);
      }
      __builtin_amdgcn_s_setprio(0);
      if (c < 5){
        asm volatile("s_waitcnt vmcnt(4)" ::: "memory");   // chunk c+1 resident
        __builtin_amdgcn_s_barrier();
      } else if (c == 5){
        asm volatile("s_waitcnt vmcnt(2)" ::: "memory");   // chunk 6 resident
        __builtin_amdgcn_s_barrier();
      } else if (c == 6){
        asm volatile("s_waitcnt vmcnt(0)" ::: "memory");   // chunk 7 resident
        __builtin_amdgcn_s_barrier();
      }
    }

    // ---- split-G epilogue (one barrier) ----
    #pragma unroll
    for (int m = 0; m < 4; m++)
      #pragma unroll
      for (int r4 = 0; r4 < 4; r4++){
        int row = m * 16 + lq * 4 + r4;
        G[q * 2176 + row * 34 + lrow]      = acc[m][0][r4];
        G[q * 2176 + row * 34 + 16 + lrow] = acc[m][1][r4];
      }
    __syncthreads();

    const int base34 = erow * 34 + ec0;
    f32x4 vr = *(const f32x4*)(G + 0 * 2176 + base34) + *(const f32x4*)(G + 4 * 2176 + base34) + bR;
    f32x4 vz = *(const f32x4*)(G + 1 * 2176 + base34) + *(const f32x4*)(G + 5 * 2176 + base34) + bZ;
    f32x4 vi = *(const f32x4*)(G + 2 * 2176 + base34) + *(const f32x4*)(G + 6 * 2176 + base34) + bI;
    f32x4 vh = *(const f32x4*)(G + 3 * 2176 + base34) + *(const f32x4*)(G + 7 * 2176 + base34) + bH;
    f32x4 vout; u16x4 hb;
    #pragma unroll
    for (int e = 0; e < 4; e++){
      float rr = 1.f / (1.f + __expf(-vr[e]));
      float zz = 1.f / (1.f + __expf(-vz[e]));
      float x  = vi[e] + rr * vh[e];
      float ex = __expf(-2.f * x);
      float nn = (1.f - ex) / (1.f + ex);
      float hn = nn + zz * (h[e] - nn);
      vout[e] = hn;
      hb[e] = f2bf(hn);
    }
    *(f32x4*)(out + (size_t)grow * 65536 + (size_t)t * 1024 + gcol) = vout;
    // sc1 write-through store (visible at LLC after vmcnt(0))
    __hip_atomic_store((unsigned long long*)(Anxt + aaddr),
                       __builtin_bit_cast(unsigned long long, hb),
                       __ATOMIC_RELAXED, __HIP_MEMORY_SCOPE_SYSTEM);
    h = vout;

    asm volatile("s_waitcnt vmcnt(0)" ::: "memory");
    __syncthreads();
    if (tid == 0)
      __hip_atomic_fetch_add(&flag[t * 8 + rb], 1,
                             __ATOMIC_RELAXED, __HIP_MEMORY_SCOPE_SYSTEM);
  }
#undef STAGE
}

// ---------------------------------------------------------------------------
extern "C" void kernel_launch(void* const* d_in, const int* in_sizes, int n_in,
                              void* d_out, int out_size, void* d_ws, size_t ws_size,
                              hipStream_t stream){
  const float* hidden = (const float*)d_in[0];
  const float* wih    = (const float*)d_in[1];
  const float* whh    = (const float*)d_in[2];
  const float* bih    = (const float*)d_in[3];
  const float* bhh    = (const float*)d_in[4];
  char*  ws   = (char*)d_ws;
  char*  WB   = ws + WB_OFF;
  float* bias = (float*)(ws + BIAS_OFF);
  char*  A0   = ws + A0_OFF;
  char*  A1   = ws + A1_OFF;
  int*   flag = (int*)(ws + FLAG_OFF);
  float* out  = (float*)d_out;

  hipLaunchKernelGGL(gru_weights, dim3(2048), dim3(256), 0, stream, wih, whh, WB);
  hipLaunchKernelGGL(gru_init,    dim3(256),  dim3(256), 0, stream,
                     hidden, bih, bhh, A0, bias, flag);
  hipLaunchKernelGGL(gru_seq,     dim3(256),  dim3(512), 0, stream,
                     A0, A1, (const char*)WB, (const float*)bias,
                     hidden, out, flag);
}

// Round 12
// 477.156 us; speedup vs baseline: 3.1320x; 1.0346x over previous
//
#include <hip/hip_runtime.h>

// DecoderGRU: h_{t+1} = GRUCell(h_t, h_t), 64 steps. Combined gates: r,z use
// (W_ih+W_hh); n keeps i_n,h_n -> one [512,1024]x[1024,4096] bf16 GEMM + fused
// GRU update per step.
// R12: persistent kernel v4. R11 + 8-deep A ring: all 8 chunk-stages issued
// at step start (LLC latency paid once), counted vmcnt(14-2c)+barrier per
// chunk (no drains), G-exchange overlays the dead A-ring (LDS 128 KB).
// B in regs (512,1 budget); sc1 LLC exchange; relaxed system flags.

typedef float  f32x4 __attribute__((ext_vector_type(4)));
typedef __bf16 bf16x8 __attribute__((ext_vector_type(8)));
typedef unsigned short u16x8 __attribute__((ext_vector_type(8)));
typedef unsigned short u16x4 __attribute__((ext_vector_type(4)));

#define GPTR(p) ((const __attribute__((address_space(1))) unsigned int*)(p))
#define LPTR(p) ((__attribute__((address_space(3))) unsigned int*)(p))

// ws layout
#define WB_OFF   0u            // 8 MB frag-packed bf16 weights
#define BIAS_OFF 8388608u      // 16 KB combined biases [4][1024]
#define A0_OFF   8404992u      // 1 MB frag-packed bf16 h (ping)
#define A1_OFF   9453568u      // 1 MB (pong)
#define FLAG_OFF 10502144u     // 2 KB flags [64 t][8 rb]

__device__ __forceinline__ unsigned short f2bf(float f){
  unsigned int u = __builtin_bit_cast(unsigned int, f);
  u = (u + 0x7FFFu + ((u >> 16) & 1u)) >> 16;
  return (unsigned short)u;
}

// ---------------------------------------------------------------------------
// B layout: byte = j*262144 + c*32768 + fb*1024 + lane*16 + (k&7)*2,
//   j=col>>5, c=k>>7, fb=(((k>>5)&3)*4+g)*2+((col>>4)&1),
//   lane=(col&15)+((k>>3)&3)*16.  gates: 0=r(+) 1=z(+) 2=i_n(ih) 3=h_n(hh)
// ---------------------------------------------------------------------------
extern "C" __global__ void gru_weights(const float* __restrict__ wih,
                                       const float* __restrict__ whh,
                                       char* __restrict__ WB){
  int gt  = blockIdx.x * 256 + threadIdx.x;   // 524288 threads
  int k0  = (gt & 127) << 3;                  // 8 k's per thread
  int gid = gt >> 7;
  int g   = gid >> 10, colg = gid & 1023;
  int srow = (g < 2) ? g * 1024 + colg : 2048 + colg;
  const float* pa = ((g == 3) ? whh : wih) + srow * 1024 + k0;
  f32x4 v0 = ((const f32x4*)pa)[0];
  f32x4 v1 = ((const f32x4*)pa)[1];
  if (g < 2){
    const float* pb = whh + srow * 1024 + k0;
    v0 += ((const f32x4*)pb)[0];
    v1 += ((const f32x4*)pb)[1];
  }
  u16x8 o;
  #pragma unroll
  for (int e = 0; e < 4; e++){ o[e] = f2bf(v0[e]); o[4 + e] = f2bf(v1[e]); }
  int cck = k0 >> 7;
  int fb  = (((k0 >> 5) & 3) * 4 + g) * 2 + ((colg >> 4) & 1);
  int lane= (colg & 15) + ((k0 >> 3) & 3) * 16;
  int addr= (colg >> 5) * 262144 + cck * 32768 + fb * 1024 + lane * 16;
  *(u16x8*)(WB + addr) = o;
}

// ---------------------------------------------------------------------------
// A layout (64-row slabs): byte = (row>>6)*131072 + (hk>>7)*16384
//   + (((hk>>5)&3)*4 + ((row&63)>>4))*1024
//   + ((row&15)+((hk>>3)&3)*16)*16 + (hk&7)*2
// ---------------------------------------------------------------------------
extern "C" __global__ void gru_init(const float* __restrict__ hidden,
                                    const float* __restrict__ bih,
                                    const float* __restrict__ bhh,
                                    char* __restrict__ A0,
                                    float* __restrict__ bias,
                                    int* __restrict__ flag){
  int gt = blockIdx.x * 256 + threadIdx.x;    // 65536 threads, 8 elems each
  int e0 = gt * 8;
  int r  = e0 >> 10, c0 = e0 & 1023;
  f32x4 v0 = ((const f32x4*)(hidden + e0))[0];
  f32x4 v1 = ((const f32x4*)(hidden + e0))[1];
  u16x8 o;
  #pragma unroll
  for (int e = 0; e < 4; e++){ o[e] = f2bf(v0[e]); o[4 + e] = f2bf(v1[e]); }
  int addr = (r >> 6) * 131072 + (c0 >> 7) * 16384
           + (((c0 >> 5) & 3) * 4 + ((r & 63) >> 4)) * 1024
           + ((r & 15) + ((c0 >> 3) & 3) * 16) * 16;
  *(u16x8*)(A0 + addr) = o;
  if (blockIdx.x < 16){
    int bi = blockIdx.x * 256 + threadIdx.x;  // 4096 bias entries
    int g = bi >> 10, c = bi & 1023;
    float v = (g == 0) ? bih[c]        + bhh[c]
            : (g == 1) ? bih[1024 + c] + bhh[1024 + c]
            : (g == 2) ? bih[2048 + c] : bhh[2048 + c];
    bias[bi] = v;
  }
  if (gt < 512) flag[gt] = 0;
}

// ---------------------------------------------------------------------------
// Persistent kernel v4. rb=bid&7, j=bid>>3. Wave wv: g=wv&3, kh=wv>>2.
// LDS: A 8-ring (8x16KB = 128KB); G [8][64][34] f32 overlays @0 after K-loop.
// Per step: poll flag[t-1,rb] -> issue ALL 8 chunk stages (sc1) ->
// {vmcnt(14-2c); barrier; 16 MFMA} x8 -> syncthreads -> G exchange ->
// epilogue -> out + sc1 Anext stores -> vmcnt(0), barrier, flag add.
// ---------------------------------------------------------------------------
extern "C" __global__ void __launch_bounds__(512, 1)
gru_seq(char* __restrict__ A0p, char* __restrict__ A1p,
        const char* __restrict__ WB, const float* __restrict__ bias,
        const float* __restrict__ hidden, float* __restrict__ out,
        int* __restrict__ flag)
{
  __shared__ __align__(16) char lds[131072];
  const int tid = threadIdx.x;
  const int wv = tid >> 6, ln = tid & 63;
  const int g = wv & 3, kh = wv >> 2;
  const int lrow = ln & 15, lq = ln >> 4;
  const int bid = blockIdx.x;
  const int rb = bid & 7, j = bid >> 3;
  const int abase = rb * 131072;
  const int bbase = j * 262144;

  // ---- B into registers ONCE for all 64 steps ----
  f32x4 braw[16][2];
  #pragma unroll
  for (int c = 0; c < 8; c++)
    #pragma unroll
    for (int p = 0; p < 2; p++)
      #pragma unroll
      for (int n = 0; n < 2; n++){
        braw[c * 2 + p][n] = *(const f32x4*)(WB + bbase + c * 32768
                               + (((kh * 2 + p) * 4 + g) * 2 + n) * 1024 + ln * 16);
        asm volatile("" : "+v"(braw[c * 2 + p][n]));
      }

  // ---- per-thread epilogue geometry; h and biases in regs ----
  const int erow = tid >> 3, ec0 = (tid & 7) * 4;
  const int grow = rb * 64 + erow, gcol = j * 32 + ec0;
  const f32x4 bR = *(const f32x4*)(bias + gcol);
  const f32x4 bZ = *(const f32x4*)(bias + 1024 + gcol);
  const f32x4 bI = *(const f32x4*)(bias + 2048 + gcol);
  const f32x4 bH = *(const f32x4*)(bias + 3072 + gcol);
  f32x4 h = *(const f32x4*)(hidden + grow * 1024 + gcol);
  const int aaddr = rb * 131072 + (j >> 2) * 16384
                  + ((j & 3) * 4 + (erow >> 4)) * 1024
                  + ((erow & 15) + ((ec0 >> 3) & 3) * 16) * 16 + (ec0 & 7) * 2;
  float* G = (float*)lds;                      // overlays A-ring post-K-loop
  const int q = kh * 4 + g;

// sc1 staging: aux = 17 (sc0|sc1) -> bypass L1/L2, read at LLC (coherent).
#define STAGE(bp, cc) do { \
    _Pragma("unroll") \
    for (int i = 0; i < 2; i++) \
      __builtin_amdgcn_global_load_lds( \
          GPTR((bp) + abase + (cc) * 16384 + tid * 16 + i * 8192), \
          LPTR(lds + (cc) * 16384 + tid * 16 + i * 8192), 16, 0, 17); \
  } while (0)

// one K-chunk: own-wave stages for chunk c retired (vmcnt literal) + barrier
// makes all waves' chunk-c data resident; then 16 MFMA.
#define CHUNK(c, VM) do { \
    asm volatile("s_waitcnt vmcnt(" #VM ")" ::: "memory"); \
    __builtin_amdgcn_s_barrier(); \
    __builtin_amdgcn_s_setprio(1); \
    _Pragma("unroll") \
    for (int p = 0; p < 2; p++){ \
      const int ks = kh * 2 + p; \
      bf16x8 a[4]; \
      _Pragma("unroll") \
      for (int m = 0; m < 4; m++) \
        a[m] = *(const bf16x8*)(lds + (c) * 16384 + (ks * 4 + m) * 1024 + ln * 16); \
      _Pragma("unroll") \
      for (int m = 0; m < 4; m++) \
        _Pragma("unroll") \
        for (int n = 0; n < 2; n++) \
          acc[m][n] = __builtin_amdgcn_mfma_f32_16x16x32_bf16( \
              a[m], __builtin_bit_cast(bf16x8, braw[(c) * 2 + p][n]), acc[m][n], 0, 0, 0); \
    } \
    __builtin_amdgcn_s_setprio(0); \
  } while (0)

  for (int t = 0; t < 64; t++){
    const char* Acur = (t & 1) ? (const char*)A1p : (const char*)A0p;
    char* Anxt = (t & 1) ? A0p : A1p;
    if (t > 0){
      if (tid == 0){
        while (__hip_atomic_load(&flag[(t - 1) * 8 + rb],
                                 __ATOMIC_RELAXED, __HIP_MEMORY_SCOPE_SYSTEM) < 32)
          __builtin_amdgcn_s_sleep(1);
      }
      __syncthreads();   // also fences prev epilogue's G reads vs new staging
    }

    f32x4 acc[4][2];
    #pragma unroll
    for (int m = 0; m < 4; m++)
      #pragma unroll
      for (int n = 0; n < 2; n++) acc[m][n] = f32x4{0.f,0.f,0.f,0.f};

    // issue the entire step's A staging at once (16 loads/thread in flight)
    STAGE(Acur, 0); STAGE(Acur, 1); STAGE(Acur, 2); STAGE(Acur, 3);
    STAGE(Acur, 4); STAGE(Acur, 5); STAGE(Acur, 6); STAGE(Acur, 7);

    CHUNK(0, 14); CHUNK(1, 12); CHUNK(2, 10); CHUNK(3, 8);
    CHUNK(4, 6);  CHUNK(5, 4);  CHUNK(6, 2);  CHUNK(7, 0);

    // ---- G exchange overlays A-ring: fence all LDS reads first ----
    __syncthreads();
    #pragma unroll
    for (int m = 0; m < 4; m++)
      #pragma unroll
      for (int r4 = 0; r4 < 4; r4++){
        int row = m * 16 + lq * 4 + r4;
        G[q * 2176 + row * 34 + lrow]      = acc[m][0][r4];
        G[q * 2176 + row * 34 + 16 + lrow] = acc[m][1][r4];
      }
    __syncthreads();

    const int base34 = erow * 34 + ec0;
    f32x4 vr = *(const f32x4*)(G + 0 * 2176 + base34) + *(const f32x4*)(G + 4 * 2176 + base34) + bR;
    f32x4 vz = *(const f32x4*)(G + 1 * 2176 + base34) + *(const f32x4*)(G + 5 * 2176 + base34) + bZ;
    f32x4 vi = *(const f32x4*)(G + 2 * 2176 + base34) + *(const f32x4*)(G + 6 * 2176 + base34) + bI;
    f32x4 vh = *(const f32x4*)(G + 3 * 2176 + base34) + *(const f32x4*)(G + 7 * 2176 + base34) + bH;
    f32x4 vout; u16x4 hb;
    #pragma unroll
    for (int e = 0; e < 4; e++){
      float rr = 1.f / (1.f + __expf(-vr[e]));
      float zz = 1.f / (1.f + __expf(-vz[e]));
      float x  = vi[e] + rr * vh[e];
      float ex = __expf(-2.f * x);
      float nn = (1.f - ex) / (1.f + ex);
      float hn = nn + zz * (h[e] - nn);
      vout[e] = hn;
      hb[e] = f2bf(hn);
    }
    *(f32x4*)(out + (size_t)grow * 65536 + (size_t)t * 1024 + gcol) = vout;
    // sc1 write-through store (visible at LLC after vmcnt(0))
    __hip_atomic_store((unsigned long long*)(Anxt + aaddr),
                       __builtin_bit_cast(unsigned long long, hb),
                       __ATOMIC_RELAXED, __HIP_MEMORY_SCOPE_SYSTEM);
    h = vout;

    asm volatile("s_waitcnt vmcnt(0)" ::: "memory");
    __syncthreads();
    if (tid == 0)
      __hip_atomic_fetch_add(&flag[t * 8 + rb], 1,
                             __ATOMIC_RELAXED, __HIP_MEMORY_SCOPE_SYSTEM);
  }
#undef STAGE
#undef CHUNK
}

// ---------------------------------------------------------------------------
extern "C" void kernel_launch(void* const* d_in, const int* in_sizes, int n_in,
                              void* d_out, int out_size, void* d_ws, size_t ws_size,
                              hipStream_t stream){
  const float* hidden = (const float*)d_in[0];
  const float* wih    = (const float*)d_in[1];
  const float* whh    = (const float*)d_in[2];
  const float* bih    = (const float*)d_in[3];
  const float* bhh    = (const float*)d_in[4];
  char*  ws   = (char*)d_ws;
  char*  WB   = ws + WB_OFF;
  float* bias = (float*)(ws + BIAS_OFF);
  char*  A0   = ws + A0_OFF;
  char*  A1   = ws + A1_OFF;
  int*   flag = (int*)(ws + FLAG_OFF);
  float* out  = (float*)d_out;

  hipLaunchKernelGGL(gru_weights, dim3(2048), dim3(256), 0, stream, wih, whh, WB);
  hipLaunchKernelGGL(gru_init,    dim3(256),  dim3(256), 0, stream,
                     hidden, bih, bhh, A0, bias, flag);
  hipLaunchKernelGGL(gru_seq,     dim3(256),  dim3(512), 0, stream,
                     A0, A1, (const char*)WB, (const float*)bias,
                     hidden, out, flag);
}

// Round 13
// 471.009 us; speedup vs baseline: 3.1729x; 1.0131x over previous
//
#include <hip/hip_runtime.h>

// DecoderGRU: h_{t+1} = GRUCell(h_t, h_t), 64 steps. Combined gates: r,z use
// (W_ih+W_hh); n keeps i_n,h_n -> one [512,1024]x[1024,4096] bf16 GEMM + fused
// GRU update per step.
// R13: persistent kernel v5. R12 + (1) A-slot ROTATION: 65 x 1MB slots, one
// per step -> every A address is written once and read once per dispatch ->
// normal cached consumer reads are stale-proof without any invalidates
// (caches are clean at dispatch start; producers write through to LLC with
// sc1). Under round-robin placement the 32 same-rb blocks share an XCD ->
// A-reads become L2 hits (LLC traffic 32 -> ~1 MB/step). G16-safe: mapping
// affects only perf. (2) Parallel per-producer flag words (no atomic-RMW
// hotspot). (3) Anext store released before the out-store drain.
// Host falls back to the R12 sc1 ping-pong variant if ws is too small.

typedef float  f32x4 __attribute__((ext_vector_type(4)));
typedef __bf16 bf16x8 __attribute__((ext_vector_type(8)));
typedef unsigned short u16x8 __attribute__((ext_vector_type(8)));
typedef unsigned short u16x4 __attribute__((ext_vector_type(4)));

#define GPTR(p) ((const __attribute__((address_space(1))) unsigned int*)(p))
#define LPTR(p) ((__attribute__((address_space(3))) unsigned int*)(p))

// ws layout
#define WB_OFF   0u            // 8 MB frag-packed bf16 weights
#define BIAS_OFF 8388608u      // 16 KB combined biases [4][1024]
#define FLAG_OFF 8404992u      // 64 KB flags [64 t][8 rb][32 j]
#define AROT_OFF 8470528u      // 65 x 1 MB A slots (rot) / 2 x 1 MB (pp)
#define WS_NEED_ROT (8470528ull + 65ull * 1048576ull)

__device__ __forceinline__ unsigned short f2bf(float f){
  unsigned int u = __builtin_bit_cast(unsigned int, f);
  u = (u + 0x7FFFu + ((u >> 16) & 1u)) >> 16;
  return (unsigned short)u;
}

// ---------------------------------------------------------------------------
// B layout: byte = j*262144 + c*32768 + fb*1024 + lane*16 + (k&7)*2,
//   j=col>>5, c=k>>7, fb=(((k>>5)&3)*4+g)*2+((col>>4)&1),
//   lane=(col&15)+((k>>3)&3)*16.  gates: 0=r(+) 1=z(+) 2=i_n(ih) 3=h_n(hh)
// ---------------------------------------------------------------------------
extern "C" __global__ void gru_weights(const float* __restrict__ wih,
                                       const float* __restrict__ whh,
                                       char* __restrict__ WB){
  int gt  = blockIdx.x * 256 + threadIdx.x;   // 524288 threads
  int k0  = (gt & 127) << 3;                  // 8 k's per thread
  int gid = gt >> 7;
  int g   = gid >> 10, colg = gid & 1023;
  int srow = (g < 2) ? g * 1024 + colg : 2048 + colg;
  const float* pa = ((g == 3) ? whh : wih) + srow * 1024 + k0;
  f32x4 v0 = ((const f32x4*)pa)[0];
  f32x4 v1 = ((const f32x4*)pa)[1];
  if (g < 2){
    const float* pb = whh + srow * 1024 + k0;
    v0 += ((const f32x4*)pb)[0];
    v1 += ((const f32x4*)pb)[1];
  }
  u16x8 o;
  #pragma unroll
  for (int e = 0; e < 4; e++){ o[e] = f2bf(v0[e]); o[4 + e] = f2bf(v1[e]); }
  int cck = k0 >> 7;
  int fb  = (((k0 >> 5) & 3) * 4 + g) * 2 + ((colg >> 4) & 1);
  int lane= (colg & 15) + ((k0 >> 3) & 3) * 16;
  int addr= (colg >> 5) * 262144 + cck * 32768 + fb * 1024 + lane * 16;
  *(u16x8*)(WB + addr) = o;
}

// ---------------------------------------------------------------------------
// A layout (64-row slabs): byte = (row>>6)*131072 + (hk>>7)*16384
//   + (((hk>>5)&3)*4 + ((row&63)>>4))*1024
//   + ((row&15)+((hk>>3)&3)*16)*16 + (hk&7)*2
// ---------------------------------------------------------------------------
extern "C" __global__ void gru_init(const float* __restrict__ hidden,
                                    const float* __restrict__ bih,
                                    const float* __restrict__ bhh,
                                    char* __restrict__ A0,
                                    float* __restrict__ bias,
                                    int* __restrict__ flag){
  int gt = blockIdx.x * 256 + threadIdx.x;    // 65536 threads, 8 elems each
  int e0 = gt * 8;
  int r  = e0 >> 10, c0 = e0 & 1023;
  f32x4 v0 = ((const f32x4*)(hidden + e0))[0];
  f32x4 v1 = ((const f32x4*)(hidden + e0))[1];
  u16x8 o;
  #pragma unroll
  for (int e = 0; e < 4; e++){ o[e] = f2bf(v0[e]); o[4 + e] = f2bf(v1[e]); }
  int addr = (r >> 6) * 131072 + (c0 >> 7) * 16384
           + (((c0 >> 5) & 3) * 4 + ((r & 63) >> 4)) * 1024
           + ((r & 15) + ((c0 >> 3) & 3) * 16) * 16;
  *(u16x8*)(A0 + addr) = o;
  if (blockIdx.x < 16){
    int bi = blockIdx.x * 256 + threadIdx.x;  // 4096 bias entries
    int g = bi >> 10, c = bi & 1023;
    float v = (g == 0) ? bih[c]        + bhh[c]
            : (g == 1) ? bih[1024 + c] + bhh[1024 + c]
            : (g == 2) ? bih[2048 + c] : bhh[2048 + c];
    bias[bi] = v;
  }
  if (gt < 16384) flag[gt] = 0;               // 64 KB flag region
}

// ---------------------------------------------------------------------------
// Persistent body. rb=bid&7, j=bid>>3. Wave wv: g=wv&3, kh=wv>>2.
// LDS: A 8-ring (8x16KB); G [8][64][34] f32 overlays @0 after the K-loop.
// ROT=true : Acur/Anxt rotate over 65 slots; cached A-reads (aux=0).
// ROT=false: 2-slot ping-pong; sc1 A-reads (aux=17) -- R12 semantics.
// ---------------------------------------------------------------------------
template<bool ROT>
__device__ __forceinline__ void gru_seq_body(
    char* __restrict__ Arot, const char* __restrict__ WB,
    const float* __restrict__ bias, const float* __restrict__ hidden,
    float* __restrict__ out, int* __restrict__ flag)
{
  __shared__ __align__(16) char lds[131072];
  const int tid = threadIdx.x;
  const int wv = tid >> 6, ln = tid & 63;
  const int g = wv & 3, kh = wv >> 2;
  const int lrow = ln & 15, lq = ln >> 4;
  const int bid = blockIdx.x;
  const int rb = bid & 7, j = bid >> 3;
  const int abase = rb * 131072;
  const int bbase = j * 262144;

  // ---- B into registers ONCE for all 64 steps ----
  f32x4 braw[16][2];
  #pragma unroll
  for (int c = 0; c < 8; c++)
    #pragma unroll
    for (int p = 0; p < 2; p++)
      #pragma unroll
      for (int n = 0; n < 2; n++){
        braw[c * 2 + p][n] = *(const f32x4*)(WB + bbase + c * 32768
                               + (((kh * 2 + p) * 4 + g) * 2 + n) * 1024 + ln * 16);
        asm volatile("" : "+v"(braw[c * 2 + p][n]));
      }

  // ---- per-thread epilogue geometry; h and biases in regs ----
  const int erow = tid >> 3, ec0 = (tid & 7) * 4;
  const int grow = rb * 64 + erow, gcol = j * 32 + ec0;
  const f32x4 bR = *(const f32x4*)(bias + gcol);
  const f32x4 bZ = *(const f32x4*)(bias + 1024 + gcol);
  const f32x4 bI = *(const f32x4*)(bias + 2048 + gcol);
  const f32x4 bH = *(const f32x4*)(bias + 3072 + gcol);
  f32x4 h = *(const f32x4*)(hidden + grow * 1024 + gcol);
  const int aaddr = rb * 131072 + (j >> 2) * 16384
                  + ((j & 3) * 4 + (erow >> 4)) * 1024
                  + ((erow & 15) + ((ec0 >> 3) & 3) * 16) * 16 + (ec0 & 7) * 2;
  float* G = (float*)lds;                      // overlays A-ring post-K-loop
  const int q = kh * 4 + g;

#define STAGE_A(bp, cc, AUX) do { \
    _Pragma("unroll") \
    for (int i = 0; i < 2; i++) \
      __builtin_amdgcn_global_load_lds( \
          GPTR((bp) + abase + (cc) * 16384 + tid * 16 + i * 8192), \
          LPTR(lds + (cc) * 16384 + tid * 16 + i * 8192), 16, 0, AUX); \
  } while (0)

#define CHUNK(c, VM) do { \
    asm volatile("s_waitcnt vmcnt(" #VM ")" ::: "memory"); \
    __builtin_amdgcn_s_barrier(); \
    __builtin_amdgcn_s_setprio(1); \
    _Pragma("unroll") \
    for (int p = 0; p < 2; p++){ \
      const int ks = kh * 2 + p; \
      bf16x8 a[4]; \
      _Pragma("unroll") \
      for (int m = 0; m < 4; m++) \
        a[m] = *(const bf16x8*)(lds + (c) * 16384 + (ks * 4 + m) * 1024 + ln * 16); \
      _Pragma("unroll") \
      for (int m = 0; m < 4; m++) \
        _Pragma("unroll") \
        for (int n = 0; n < 2; n++) \
          acc[m][n] = __builtin_amdgcn_mfma_f32_16x16x32_bf16( \
              a[m], __builtin_bit_cast(bf16x8, braw[(c) * 2 + p][n]), acc[m][n], 0, 0, 0); \
    } \
    __builtin_amdgcn_s_setprio(0); \
  } while (0)

  for (int t = 0; t < 64; t++){
    const char* Acur = Arot + (size_t)(ROT ? t : (t & 1)) * 1048576u;
    char* Anxt = Arot + (size_t)(ROT ? (t + 1) : ((t + 1) & 1)) * 1048576u;
    if (t > 0){
      // parallel poll: 32 producer flag words, one per lane (lanes 32-63 dup)
      if (tid < 64){
        const int* fp = flag + ((t - 1) * 8 + rb) * 32 + (tid & 31);
        for (;;){
          int v = __hip_atomic_load(fp, __ATOMIC_RELAXED, __HIP_MEMORY_SCOPE_SYSTEM);
          if (__all(v != 0)) break;
          __builtin_amdgcn_s_sleep(1);
        }
      }
      __syncthreads();   // also fences prev epilogue's G reads vs new staging
    }

    f32x4 acc[4][2];
    #pragma unroll
    for (int m = 0; m < 4; m++)
      #pragma unroll
      for (int n = 0; n < 2; n++) acc[m][n] = f32x4{0.f,0.f,0.f,0.f};

    // issue the entire step's A staging at once (16 loads/thread in flight)
    if constexpr (ROT){
      STAGE_A(Acur, 0, 0); STAGE_A(Acur, 1, 0); STAGE_A(Acur, 2, 0); STAGE_A(Acur, 3, 0);
      STAGE_A(Acur, 4, 0); STAGE_A(Acur, 5, 0); STAGE_A(Acur, 6, 0); STAGE_A(Acur, 7, 0);
    } else {
      STAGE_A(Acur, 0, 17); STAGE_A(Acur, 1, 17); STAGE_A(Acur, 2, 17); STAGE_A(Acur, 3, 17);
      STAGE_A(Acur, 4, 17); STAGE_A(Acur, 5, 17); STAGE_A(Acur, 6, 17); STAGE_A(Acur, 7, 17);
    }

    CHUNK(0, 14); CHUNK(1, 12); CHUNK(2, 10); CHUNK(3, 8);
    CHUNK(4, 6);  CHUNK(5, 4);  CHUNK(6, 2);  CHUNK(7, 0);

    // ---- G exchange overlays A-ring: fence all LDS reads first ----
    __syncthreads();
    #pragma unroll
    for (int m = 0; m < 4; m++)
      #pragma unroll
      for (int r4 = 0; r4 < 4; r4++){
        int row = m * 16 + lq * 4 + r4;
        G[q * 2176 + row * 34 + lrow]      = acc[m][0][r4];
        G[q * 2176 + row * 34 + 16 + lrow] = acc[m][1][r4];
      }
    __syncthreads();

    const int base34 = erow * 34 + ec0;
    f32x4 vr = *(const f32x4*)(G + 0 * 2176 + base34) + *(const f32x4*)(G + 4 * 2176 + base34) + bR;
    f32x4 vz = *(const f32x4*)(G + 1 * 2176 + base34) + *(const f32x4*)(G + 5 * 2176 + base34) + bZ;
    f32x4 vi = *(const f32x4*)(G + 2 * 2176 + base34) + *(const f32x4*)(G + 6 * 2176 + base34) + bI;
    f32x4 vh = *(const f32x4*)(G + 3 * 2176 + base34) + *(const f32x4*)(G + 7 * 2176 + base34) + bH;
    f32x4 vout; u16x4 hb;
    #pragma unroll
    for (int e = 0; e < 4; e++){
      float rr = 1.f / (1.f + __expf(-vr[e]));
      float zz = 1.f / (1.f + __expf(-vz[e]));
      float x  = vi[e] + rr * vh[e];
      float ex = __expf(-2.f * x);
      float nn = (1.f - ex) / (1.f + ex);
      float hn = nn + zz * (h[e] - nn);
      vout[e] = hn;
      hb[e] = f2bf(hn);
    }
    // Anext FIRST (older in program order; write-through to LLC), then out.
    __hip_atomic_store((unsigned long long*)(Anxt + aaddr),
                       __builtin_bit_cast(unsigned long long, hb),
                       __ATOMIC_RELAXED, __HIP_MEMORY_SCOPE_SYSTEM);
    asm volatile("" ::: "memory");             // keep store order at codegen
    *(f32x4*)(out + (size_t)grow * 65536 + (size_t)t * 1024 + gcol) = vout;
    h = vout;

    // retire the Anext store (oldest) only; out-store drains off-path
    asm volatile("s_waitcnt vmcnt(1)" ::: "memory");
    __syncthreads();
    if (tid == 0)
      __hip_atomic_store(&flag[(t * 8 + rb) * 32 + j], 1,
                         __ATOMIC_RELAXED, __HIP_MEMORY_SCOPE_SYSTEM);
  }
#undef STAGE_A
#undef CHUNK
}

extern "C" __global__ void __launch_bounds__(512, 1)
gru_seq_rot(char* Arot, const char* WB, const float* bias,
            const float* hidden, float* out, int* flag){
  gru_seq_body<true>(Arot, WB, bias, hidden, out, flag);
}

extern "C" __global__ void __launch_bounds__(512, 1)
gru_seq_pp(char* Arot, const char* WB, const float* bias,
           const float* hidden, float* out, int* flag){
  gru_seq_body<false>(Arot, WB, bias, hidden, out, flag);
}

// ---------------------------------------------------------------------------
extern "C" void kernel_launch(void* const* d_in, const int* in_sizes, int n_in,
                              void* d_out, int out_size, void* d_ws, size_t ws_size,
                              hipStream_t stream){
  const float* hidden = (const float*)d_in[0];
  const float* wih    = (const float*)d_in[1];
  const float* whh    = (const float*)d_in[2];
  const float* bih    = (const float*)d_in[3];
  const float* bhh    = (const float*)d_in[4];
  char*  ws   = (char*)d_ws;
  char*  WB   = ws + WB_OFF;
  float* bias = (float*)(ws + BIAS_OFF);
  int*   flag = (int*)(ws + FLAG_OFF);
  char*  Arot = ws + AROT_OFF;
  float* out  = (float*)d_out;

  hipLaunchKernelGGL(gru_weights, dim3(2048), dim3(256), 0, stream, wih, whh, WB);
  hipLaunchKernelGGL(gru_init,    dim3(256),  dim3(256), 0, stream,
                     hidden, bih, bhh, Arot, bias, flag);
  if (ws_size >= WS_NEED_ROT)
    hipLaunchKernelGGL(gru_seq_rot, dim3(256), dim3(512), 0, stream,
                       Arot, (const char*)WB, (const float*)bias,
                       hidden, out, flag);
  else
    hipLaunchKernelGGL(gru_seq_pp,  dim3(256), dim3(512), 0, stream,
                       Arot, (const char*)WB, (const float*)bias,
                       hidden, out, flag);
}

// Round 14
// 465.290 us; speedup vs baseline: 3.2119x; 1.0123x over previous
//
#include <hip/hip_runtime.h>

// DecoderGRU: h_{t+1} = GRUCell(h_t, h_t), 64 steps. Combined gates: r,z use
// (W_ih+W_hh); n keeps i_n,h_n -> one [512,1024]x[1024,4096] bf16 GEMM + fused
// GRU update per step.
// R14: persistent kernel v6 = R13 with barrier thinning. K-loop gates 8 -> 2
// (vmcnt(12) -> MFMA 0-1, vmcnt(0) -> MFMA 2-7); epilogue stores drained
// before flag so nothing leaks into the next step's vmcnt window; 6 block
// barriers/step (was 12). Rot A slots + parallel per-producer flags + B in
// regs (512,1) + 8-deep A ring with G overlay: unchanged (R12/R13-proven).

typedef float  f32x4 __attribute__((ext_vector_type(4)));
typedef __bf16 bf16x8 __attribute__((ext_vector_type(8)));
typedef unsigned short u16x8 __attribute__((ext_vector_type(8)));
typedef unsigned short u16x4 __attribute__((ext_vector_type(4)));

#define GPTR(p) ((const __attribute__((address_space(1))) unsigned int*)(p))
#define LPTR(p) ((__attribute__((address_space(3))) unsigned int*)(p))

// ws layout
#define WB_OFF   0u            // 8 MB frag-packed bf16 weights
#define BIAS_OFF 8388608u      // 16 KB combined biases [4][1024]
#define FLAG_OFF 8404992u      // 64 KB flags [64 t][8 rb][32 j]
#define AROT_OFF 8470528u      // 65 x 1 MB A slots (rot) / 2 x 1 MB (pp)
#define WS_NEED_ROT (8470528ull + 65ull * 1048576ull)

__device__ __forceinline__ unsigned short f2bf(float f){
  unsigned int u = __builtin_bit_cast(unsigned int, f);
  u = (u + 0x7FFFu + ((u >> 16) & 1u)) >> 16;
  return (unsigned short)u;
}

// ---------------------------------------------------------------------------
// B layout: byte = j*262144 + c*32768 + fb*1024 + lane*16 + (k&7)*2,
//   j=col>>5, c=k>>7, fb=(((k>>5)&3)*4+g)*2+((col>>4)&1),
//   lane=(col&15)+((k>>3)&3)*16.  gates: 0=r(+) 1=z(+) 2=i_n(ih) 3=h_n(hh)
// ---------------------------------------------------------------------------
extern "C" __global__ void gru_weights(const float* __restrict__ wih,
                                       const float* __restrict__ whh,
                                       char* __restrict__ WB){
  int gt  = blockIdx.x * 256 + threadIdx.x;   // 524288 threads
  int k0  = (gt & 127) << 3;                  // 8 k's per thread
  int gid = gt >> 7;
  int g   = gid >> 10, colg = gid & 1023;
  int srow = (g < 2) ? g * 1024 + colg : 2048 + colg;
  const float* pa = ((g == 3) ? whh : wih) + srow * 1024 + k0;
  f32x4 v0 = ((const f32x4*)pa)[0];
  f32x4 v1 = ((const f32x4*)pa)[1];
  if (g < 2){
    const float* pb = whh + srow * 1024 + k0;
    v0 += ((const f32x4*)pb)[0];
    v1 += ((const f32x4*)pb)[1];
  }
  u16x8 o;
  #pragma unroll
  for (int e = 0; e < 4; e++){ o[e] = f2bf(v0[e]); o[4 + e] = f2bf(v1[e]); }
  int cck = k0 >> 7;
  int fb  = (((k0 >> 5) & 3) * 4 + g) * 2 + ((colg >> 4) & 1);
  int lane= (colg & 15) + ((k0 >> 3) & 3) * 16;
  int addr= (colg >> 5) * 262144 + cck * 32768 + fb * 1024 + lane * 16;
  *(u16x8*)(WB + addr) = o;
}

// ---------------------------------------------------------------------------
// A layout (64-row slabs): byte = (row>>6)*131072 + (hk>>7)*16384
//   + (((hk>>5)&3)*4 + ((row&63)>>4))*1024
//   + ((row&15)+((hk>>3)&3)*16)*16 + (hk&7)*2
// ---------------------------------------------------------------------------
extern "C" __global__ void gru_init(const float* __restrict__ hidden,
                                    const float* __restrict__ bih,
                                    const float* __restrict__ bhh,
                                    char* __restrict__ A0,
                                    float* __restrict__ bias,
                                    int* __restrict__ flag){
  int gt = blockIdx.x * 256 + threadIdx.x;    // 65536 threads, 8 elems each
  int e0 = gt * 8;
  int r  = e0 >> 10, c0 = e0 & 1023;
  f32x4 v0 = ((const f32x4*)(hidden + e0))[0];
  f32x4 v1 = ((const f32x4*)(hidden + e0))[1];
  u16x8 o;
  #pragma unroll
  for (int e = 0; e < 4; e++){ o[e] = f2bf(v0[e]); o[4 + e] = f2bf(v1[e]); }
  int addr = (r >> 6) * 131072 + (c0 >> 7) * 16384
           + (((c0 >> 5) & 3) * 4 + ((r & 63) >> 4)) * 1024
           + ((r & 15) + ((c0 >> 3) & 3) * 16) * 16;
  *(u16x8*)(A0 + addr) = o;
  if (blockIdx.x < 16){
    int bi = blockIdx.x * 256 + threadIdx.x;  // 4096 bias entries
    int g = bi >> 10, c = bi & 1023;
    float v = (g == 0) ? bih[c]        + bhh[c]
            : (g == 1) ? bih[1024 + c] + bhh[1024 + c]
            : (g == 2) ? bih[2048 + c] : bhh[2048 + c];
    bias[bi] = v;
  }
  if (gt < 16384) flag[gt] = 0;               // 64 KB flag region
}

// ---------------------------------------------------------------------------
// Persistent body. rb=bid&7, j=bid>>3. Wave wv: g=wv&3, kh=wv>>2.
// LDS: A 8-ring (8x16KB); G [8][64][34] f32 overlays @0 after the K-loop.
// Per step (6 barriers): poll+bar -> stage all 8 -> vmcnt(12)+bar ->
// MFMA 0-1 -> vmcnt(0)+bar -> MFMA 2-7 -> bar -> G writes -> bar ->
// GRU + out/Anext stores -> vmcnt(0)+bar -> flag store.
// ---------------------------------------------------------------------------
template<bool ROT>
__device__ __forceinline__ void gru_seq_body(
    char* __restrict__ Arot, const char* __restrict__ WB,
    const float* __restrict__ bias, const float* __restrict__ hidden,
    float* __restrict__ out, int* __restrict__ flag)
{
  __shared__ __align__(16) char lds[131072];
  const int tid = threadIdx.x;
  const int wv = tid >> 6, ln = tid & 63;
  const int g = wv & 3, kh = wv >> 2;
  const int lrow = ln & 15, lq = ln >> 4;
  const int bid = blockIdx.x;
  const int rb = bid & 7, j = bid >> 3;
  const int abase = rb * 131072;
  const int bbase = j * 262144;

  // ---- B into registers ONCE for all 64 steps ----
  f32x4 braw[16][2];
  #pragma unroll
  for (int c = 0; c < 8; c++)
    #pragma unroll
    for (int p = 0; p < 2; p++)
      #pragma unroll
      for (int n = 0; n < 2; n++){
        braw[c * 2 + p][n] = *(const f32x4*)(WB + bbase + c * 32768
                               + (((kh * 2 + p) * 4 + g) * 2 + n) * 1024 + ln * 16);
        asm volatile("" : "+v"(braw[c * 2 + p][n]));
      }

  // ---- per-thread epilogue geometry; h and biases in regs ----
  const int erow = tid >> 3, ec0 = (tid & 7) * 4;
  const int grow = rb * 64 + erow, gcol = j * 32 + ec0;
  const f32x4 bR = *(const f32x4*)(bias + gcol);
  const f32x4 bZ = *(const f32x4*)(bias + 1024 + gcol);
  const f32x4 bI = *(const f32x4*)(bias + 2048 + gcol);
  const f32x4 bH = *(const f32x4*)(bias + 3072 + gcol);
  f32x4 h = *(const f32x4*)(hidden + grow * 1024 + gcol);
  const int aaddr = rb * 131072 + (j >> 2) * 16384
                  + ((j & 3) * 4 + (erow >> 4)) * 1024
                  + ((erow & 15) + ((ec0 >> 3) & 3) * 16) * 16 + (ec0 & 7) * 2;
  float* G = (float*)lds;                      // overlays A-ring post-K-loop
  const int q = kh * 4 + g;

#define STAGE_A(bp, cc, AUX) do { \
    _Pragma("unroll") \
    for (int i = 0; i < 2; i++) \
      __builtin_amdgcn_global_load_lds( \
          GPTR((bp) + abase + (cc) * 16384 + tid * 16 + i * 8192), \
          LPTR(lds + (cc) * 16384 + tid * 16 + i * 8192), 16, 0, AUX); \
  } while (0)

// one K-chunk of MFMA, no sync (data already gated resident)
#define CHUNK_NB(c) do { \
    _Pragma("unroll") \
    for (int p = 0; p < 2; p++){ \
      const int ks = kh * 2 + p; \
      bf16x8 a[4]; \
      _Pragma("unroll") \
      for (int m = 0; m < 4; m++) \
        a[m] = *(const bf16x8*)(lds + (c) * 16384 + (ks * 4 + m) * 1024 + ln * 16); \
      _Pragma("unroll") \
      for (int m = 0; m < 4; m++) \
        _Pragma("unroll") \
        for (int n = 0; n < 2; n++) \
          acc[m][n] = __builtin_amdgcn_mfma_f32_16x16x32_bf16( \
              a[m], __builtin_bit_cast(bf16x8, braw[(c) * 2 + p][n]), acc[m][n], 0, 0, 0); \
    } \
  } while (0)

  for (int t = 0; t < 64; t++){
    const char* Acur = Arot + (size_t)(ROT ? t : (t & 1)) * 1048576u;
    char* Anxt = Arot + (size_t)(ROT ? (t + 1) : ((t + 1) & 1)) * 1048576u;
    if (t > 0){
      // parallel poll: 32 producer flag words, one per lane (lanes 32-63 dup)
      if (tid < 64){
        const int* fp = flag + ((t - 1) * 8 + rb) * 32 + (tid & 31);
        for (;;){
          int v = __hip_atomic_load(fp, __ATOMIC_RELAXED, __HIP_MEMORY_SCOPE_SYSTEM);
          if (__all(v != 0)) break;
          __builtin_amdgcn_s_sleep(1);
        }
      }
      __syncthreads();   // (1) fences prev G reads vs new staging
    }

    f32x4 acc[4][2];
    #pragma unroll
    for (int m = 0; m < 4; m++)
      #pragma unroll
      for (int n = 0; n < 2; n++) acc[m][n] = f32x4{0.f,0.f,0.f,0.f};

    // issue the entire step's A staging at once (16 loads/thread in flight)
    if constexpr (ROT){
      STAGE_A(Acur, 0, 0); STAGE_A(Acur, 1, 0); STAGE_A(Acur, 2, 0); STAGE_A(Acur, 3, 0);
      STAGE_A(Acur, 4, 0); STAGE_A(Acur, 5, 0); STAGE_A(Acur, 6, 0); STAGE_A(Acur, 7, 0);
    } else {
      STAGE_A(Acur, 0, 17); STAGE_A(Acur, 1, 17); STAGE_A(Acur, 2, 17); STAGE_A(Acur, 3, 17);
      STAGE_A(Acur, 4, 17); STAGE_A(Acur, 5, 17); STAGE_A(Acur, 6, 17); STAGE_A(Acur, 7, 17);
    }

    // phase 1: chunks 0-1 resident -> start MFMA early
    asm volatile("s_waitcnt vmcnt(12)" ::: "memory");
    __builtin_amdgcn_s_barrier();              // (2)
    __builtin_amdgcn_s_setprio(1);
    CHUNK_NB(0); CHUNK_NB(1);
    __builtin_amdgcn_s_setprio(0);

    // phase 2: everything resident -> uninterrupted MFMA run
    asm volatile("s_waitcnt vmcnt(0)" ::: "memory");
    __builtin_amdgcn_s_barrier();              // (3)
    __builtin_amdgcn_s_setprio(1);
    CHUNK_NB(2); CHUNK_NB(3); CHUNK_NB(4); CHUNK_NB(5); CHUNK_NB(6); CHUNK_NB(7);
    __builtin_amdgcn_s_setprio(0);

    // ---- G exchange overlays A-ring: fence all LDS reads first ----
    __syncthreads();                           // (4)
    #pragma unroll
    for (int m = 0; m < 4; m++)
      #pragma unroll
      for (int r4 = 0; r4 < 4; r4++){
        int row = m * 16 + lq * 4 + r4;
        G[q * 2176 + row * 34 + lrow]      = acc[m][0][r4];
        G[q * 2176 + row * 34 + 16 + lrow] = acc[m][1][r4];
      }
    __syncthreads();                           // (5)

    const int base34 = erow * 34 + ec0;
    f32x4 vr = *(const f32x4*)(G + 0 * 2176 + base34) + *(const f32x4*)(G + 4 * 2176 + base34) + bR;
    f32x4 vz = *(const f32x4*)(G + 1 * 2176 + base34) + *(const f32x4*)(G + 5 * 2176 + base34) + bZ;
    f32x4 vi = *(const f32x4*)(G + 2 * 2176 + base34) + *(const f32x4*)(G + 6 * 2176 + base34) + bI;
    f32x4 vh = *(const f32x4*)(G + 3 * 2176 + base34) + *(const f32x4*)(G + 7 * 2176 + base34) + bH;
    f32x4 vout; u16x4 hb;
    #pragma unroll
    for (int e = 0; e < 4; e++){
      float rr = 1.f / (1.f + __expf(-vr[e]));
      float zz = 1.f / (1.f + __expf(-vz[e]));
      float x  = vi[e] + rr * vh[e];
      float ex = __expf(-2.f * x);
      float nn = (1.f - ex) / (1.f + ex);
      float hn = nn + zz * (h[e] - nn);
      vout[e] = hn;
      hb[e] = f2bf(hn);
    }
    // issue both stores, then drain BOTH before flag -> nothing outstanding
    // leaks into the next step's vmcnt window.
    __hip_atomic_store((unsigned long long*)(Anxt + aaddr),
                       __builtin_bit_cast(unsigned long long, hb),
                       __ATOMIC_RELAXED, __HIP_MEMORY_SCOPE_SYSTEM);
    *(f32x4*)(out + (size_t)grow * 65536 + (size_t)t * 1024 + gcol) = vout;
    h = vout;

    asm volatile("s_waitcnt vmcnt(0)" ::: "memory");
    __syncthreads();                           // (6)
    if (tid == 0)
      __hip_atomic_store(&flag[(t * 8 + rb) * 32 + j], 1,
                         __ATOMIC_RELAXED, __HIP_MEMORY_SCOPE_SYSTEM);
  }
#undef STAGE_A
#undef CHUNK_NB
}

extern "C" __global__ void __launch_bounds__(512, 1)
gru_seq_rot(char* Arot, const char* WB, const float* bias,
            const float* hidden, float* out, int* flag){
  gru_seq_body<true>(Arot, WB, bias, hidden, out, flag);
}

extern "C" __global__ void __launch_bounds__(512, 1)
gru_seq_pp(char* Arot, const char* WB, const float* bias,
           const float* hidden, float* out, int* flag){
  gru_seq_body<false>(Arot, WB, bias, hidden, out, flag);
}

// ---------------------------------------------------------------------------
extern "C" void kernel_launch(void* const* d_in, const int* in_sizes, int n_in,
                              void* d_out, int out_size, void* d_ws, size_t ws_size,
                              hipStream_t stream){
  const float* hidden = (const float*)d_in[0];
  const float* wih    = (const float*)d_in[1];
  const float* whh    = (const float*)d_in[2];
  const float* bih    = (const float*)d_in[3];
  const float* bhh    = (const float*)d_in[4];
  char*  ws   = (char*)d_ws;
  char*  WB   = ws + WB_OFF;
  float* bias = (float*)(ws + BIAS_OFF);
  int*   flag = (int*)(ws + FLAG_OFF);
  char*  Arot = ws + AROT_OFF;
  float* out  = (float*)d_out;

  hipLaunchKernelGGL(gru_weights, dim3(2048), dim3(256), 0, stream, wih, whh, WB);
  hipLaunchKernelGGL(gru_init,    dim3(256),  dim3(256), 0, stream,
                     hidden, bih, bhh, Arot, bias, flag);
  if (ws_size >= WS_NEED_ROT)
    hipLaunchKernelGGL(gru_seq_rot, dim3(256), dim3(512), 0, stream,
                       Arot, (const char*)WB, (const float*)bias,
                       hidden, out, flag);
  else
    hipLaunchKernelGGL(gru_seq_pp,  dim3(256), dim3(512), 0, stream,
                       Arot, (const char*)WB, (const float*)bias,
                       hidden, out, flag);
}